// Round 6
// baseline (326.715 us; speedup 1.0000x reference)
//
#include <hip/hip_runtime.h>
#include <math.h>

// QNN: all gates are GF(2)-convolutions and the CNOT cascade is a linear bit
// permutation P  =>  the 16 initial basis states evolve into XOR-translates
// of ONE simulated state: probs_j(i) = probs_0(i ^ P^4(j)).
// Simulate a single 2^18 complex state (2 MB), then
// logits[j][o] = sum_d probs_0(d ^ T_j) * W[o][d] + b[o];
// out[b][o] = sigmoid(logits[idx_b][o]).
//
// Bit convention: wire w <-> bit p = 17-w.  P: out bit q (q<=16) =
// parity(i>>q); out bit 17 = parity(i & 0x1FFFF).
//
// All circuit passes use 256 blocks (full machine). Per layer:
//   kA : 10 gates on bits 0..9, contiguous 1024-element LDS tiles.
//   kBC: 8 gates on bits 10..17 + perm P scatter; tile = 256 hi x 4 lo.

#define DIM (1 << 18)
#define NW 18
#define CH 64                       // k_mm chunk (d per LDS stage)
#define CPB 4                       // chunks per k_mm block
#define NMM 1024                    // k_mm blocks = DIM/(CH*CPB)

__device__ __forceinline__ unsigned perm18(unsigned i) {
    unsigned s = i;
    s ^= s >> 1; s ^= s >> 2; s ^= s >> 4; s ^= s >> 8; s ^= s >> 16;
    unsigned out = s & 0x1FFFFu;
    out |= ((s ^ (i >> 17)) & 1u) << 17;
    return out;
}

__device__ __forceinline__ unsigned pinv18(unsigned b) {
    unsigned t = b & 0x1FFFFu;                 // s_0..s_16
    unsigned u = (t ^ (t >> 1)) & 0xFFFFu;     // i_0..i_15
    unsigned i17 = ((b >> 17) ^ t) & 1u;
    unsigned i16 = ((t >> 16) ^ i17) & 1u;
    return u | (i16 << 16) | (i17 << 17);
}

__device__ __forceinline__ void bfly(float2& a0, float2& a1, float c, float s) {
    float2 n0 = make_float2(c * a0.x + s * a1.y, c * a0.y - s * a1.x);
    float2 n1 = make_float2(c * a1.x + s * a0.y, c * a1.y - s * a0.x);
    a0 = n0; a1 = n1;
}

// ---- kInit: analytic layer-0 (post-P basis) + layer-1 gates bits 0..9 ------
__global__ __launch_bounds__(256) void kInit(float2* buf, const float* qw) {
    __shared__ float2 t[1024];
    __shared__ float2 gsh[10];
    int tid = threadIdx.x;
    if (tid < 10) {
        float th = qw[1 * NW + (17 - tid)] * 0.5f;
        gsh[tid] = make_float2(cosf(th), sinf(th));
    }
    float c[NW], s[NW];
#pragma unroll
    for (int w = 0; w < NW; ++w) {
        float th = qw[w] * 0.5f;
        c[w] = cosf(th); s[w] = sinf(th);
    }
    unsigned base = blockIdx.x * 1024u;
#pragma unroll
    for (int r = 0; r < 4; ++r) {
        int k = tid + r * 256;
        unsigned i = pinv18(base + k);
        float m = 1.0f;
#pragma unroll
        for (int p = 0; p < 18; ++p)
            m *= ((i >> p) & 1u) ? s[17 - p] : c[17 - p];
        int k4 = __popc(i) & 3;
        float2 a;
        if      (k4 == 0) a = make_float2( m, 0.f);
        else if (k4 == 1) a = make_float2(0.f, -m);
        else if (k4 == 2) a = make_float2(-m, 0.f);
        else              a = make_float2(0.f,  m);
        t[k] = a;
    }
    __syncthreads();
    for (int p = 0; p <= 9; ++p) {
        float2 g = gsh[p];
        int mlow = (1 << p) - 1;
        for (int k = tid; k < 512; k += 256) {
            int i0 = ((k >> p) << (p + 1)) | (k & mlow);
            int i1 = i0 | (1 << p);
            bfly(t[i0], t[i1], g.x, g.y);
        }
        __syncthreads();
    }
#pragma unroll
    for (int r = 0; r < 4; ++r) {
        int k = tid + r * 256;
        buf[base + k] = t[k];
    }
}

// ---- kA: 10 RX gates on bits 0..9, in-place, contiguous 1024 tiles ---------
__global__ __launch_bounds__(256) void kA(float2* buf, const float* qw, int layer) {
    __shared__ float2 t[1024];
    __shared__ float2 gsh[10];
    int tid = threadIdx.x;
    if (tid < 10) {
        float th = qw[layer * NW + (17 - tid)] * 0.5f;
        gsh[tid] = make_float2(cosf(th), sinf(th));
    }
    unsigned base = blockIdx.x * 1024u;
#pragma unroll
    for (int r = 0; r < 4; ++r) t[tid + r * 256] = buf[base + tid + r * 256];
    __syncthreads();
    for (int p = 0; p <= 9; ++p) {
        float2 g = gsh[p];
        int mlow = (1 << p) - 1;
        for (int k = tid; k < 512; k += 256) {
            int i0 = ((k >> p) << (p + 1)) | (k & mlow);
            int i1 = i0 | (1 << p);
            bfly(t[i0], t[i1], g.x, g.y);
        }
        __syncthreads();
    }
#pragma unroll
    for (int r = 0; r < 4; ++r) buf[base + tid + r * 256] = t[tid + r * 256];
}

// ---- kBC: 8 RX gates on bits 10..17 + perm P scatter -----------------------
// tile: h in [0,256) = bits 10..17, lo in [0,4) = bits 0..1; block = bits 2..9.
// If probs != nullptr, emit |amp|^2 (final layer).
__global__ __launch_bounds__(256) void kBC(const float2* __restrict__ in, float2* out,
                                           float* probs, const float* qw, int layer) {
    __shared__ float2 t[1024];
    __shared__ float2 gsh[8];
    int tid = threadIdx.x;
    if (tid < 8) {                              // bit 10+q -> wire 7-q
        float th = qw[layer * NW + (7 - tid)] * 0.5f;
        gsh[tid] = make_float2(cosf(th), sinf(th));
    }
    unsigned m = blockIdx.x;                    // bits 2..9
#pragma unroll
    for (int r = 0; r < 4; ++r) {
        int k = tid + r * 256;
        int h = k >> 2, lo = k & 3;
        t[k] = in[((unsigned)h << 10) | (m << 2) | lo];
    }
    __syncthreads();
    for (int q = 0; q <= 7; ++q) {
        float2 g = gsh[q];
        int mq = (1 << q) - 1;
        for (int k = tid; k < 512; k += 256) {
            int hh = k >> 2, lo = k & 3;
            int h0 = ((hh >> q) << (q + 1)) | (hh & mq);
            int h1 = h0 | (1 << q);
            bfly(t[(h0 << 2) | lo], t[(h1 << 2) | lo], g.x, g.y);
        }
        __syncthreads();
    }
    if (probs) {
#pragma unroll
        for (int r = 0; r < 4; ++r) {
            int k = tid + r * 256;
            int h = k >> 2, lo = k & 3;
            unsigned i = ((unsigned)h << 10) | (m << 2) | lo;
            float2 a = t[k];
            probs[perm18(i)] = a.x * a.x + a.y * a.y;
        }
    } else {
#pragma unroll
        for (int r = 0; r < 4; ++r) {
            int k = tid + r * 256;
            int h = k >> 2, lo = k & 3;
            unsigned i = ((unsigned)h << 10) | (m << 2) | lo;
            out[perm18(i)] = t[k];
        }
    }
}

// ---- logits partials: 1024 blocks, dbuf LDS, 4j x 8o register tile ---------
// thread = (dq:3 | jg:2 | og:3); j = jg*4+u, o = og + 8*v.
__global__ __launch_bounds__(256, 3) void k_mm(const float* __restrict__ p0,
                                               const float* __restrict__ W,
                                               float* __restrict__ partial) {
    __shared__ float Wl[2][64][68];
    __shared__ float Pl[2][16][68];
    int tid = threadIdx.x;
    // P-translate table (per thread, for staging rows sj, sj+4, sj+8, sj+12)
    int sj = tid >> 6;                     // 0..3
    unsigned Tj[4];
#pragma unroll
    for (int i = 0; i < 4; ++i) {
        unsigned v = (unsigned)(i * 4 + sj);
#pragma unroll
        for (int r = 0; r < 4; ++r) v = perm18(v);
        Tj[i] = v;
    }
    int so = tid >> 4;                     // 0..15 (W row in group)
    int sd = (tid & 15) * 4;               // float4 col
    int sm = tid & 63;
    int dq = tid >> 5;                     // 0..7 (8 d's each)
    int jg = (tid >> 3) & 3;               // 0..3
    int og = tid & 7;                      // 0..7
    unsigned d00 = (unsigned)blockIdx.x * (CH * CPB);

    float4 wreg[4];
    float  preg[4];
    float acc[4][8] = {};

    auto loadw = [&](unsigned d0) {
#pragma unroll
        for (int i = 0; i < 4; ++i)
            wreg[i] = *(const float4*)&W[(size_t)(i * 16 + so) * DIM + d0 + sd];
    };
    auto loadp = [&](unsigned d0) {
#pragma unroll
        for (int i = 0; i < 4; ++i)
            preg[i] = p0[(d0 ^ (Tj[i] & ~63u)) + sm];
    };
    auto commit = [&](int b) {
#pragma unroll
        for (int i = 0; i < 4; ++i)
            *(float4*)&Wl[b][i * 16 + so][sd] = wreg[i];
#pragma unroll
        for (int i = 0; i < 4; ++i)
            Pl[b][i * 4 + sj][sm ^ (Tj[i] & 63u)] = preg[i];
    };
    auto compute = [&](int b) {
#pragma unroll
        for (int it = 0; it < 2; ++it) {
            int d = dq * 8 + it * 4;
            float4 pv[4], wv[8];
#pragma unroll
            for (int u = 0; u < 4; ++u) pv[u] = *(const float4*)&Pl[b][jg * 4 + u][d];
#pragma unroll
            for (int v = 0; v < 8; ++v) wv[v] = *(const float4*)&Wl[b][og + 8 * v][d];
#pragma unroll
            for (int u = 0; u < 4; ++u)
#pragma unroll
                for (int v = 0; v < 8; ++v)
                    acc[u][v] += pv[u].x * wv[v].x + pv[u].y * wv[v].y
                               + pv[u].z * wv[v].z + pv[u].w * wv[v].w;
        }
    };

    loadw(d00); loadp(d00);
    commit(0);
    __syncthreads();
#pragma unroll
    for (int cc = 0; cc < CPB; ++cc) {
        if (cc + 1 < CPB) {                // issue next chunk's global loads
            unsigned d0 = d00 + (unsigned)(cc + 1) * CH;
            loadw(d0); loadp(d0);
        }
        compute(cc & 1);
        if (cc + 1 < CPB) commit((cc + 1) & 1);
        __syncthreads();
    }

    // reduce the 8 dq groups (reuse Wl as 32 KB scratch)
    float* red = &Wl[0][0][0];
#pragma unroll
    for (int u = 0; u < 4; ++u)
#pragma unroll
        for (int v = 0; v < 8; ++v)
            red[(u * 8 + v) * 256 + tid] = acc[u][v];
    __syncthreads();
#pragma unroll
    for (int r = 0; r < 4; ++r) {
        int g = tid + r * 256;             // 1024 outputs: j*64+o
        int j = g >> 6, o = g & 63;
        int u = j & 3, jgg = j >> 2, vv = o >> 3, ogg = o & 7;
        int slotbase = (u * 8 + vv) * 256 + jgg * 8 + ogg;
        float ssum = 0.f;
#pragma unroll
        for (int q = 0; q < 8; ++q) ssum += red[slotbase + q * 32];
        partial[(size_t)blockIdx.x * 1024 + g] = ssum;
    }
}

// ---- finalize: reduce partials -> logits; per-batch lookup + sigmoid -------
// 64 blocks; block b owns idx = b>>2, o in [(b&3)*16, +16).
__global__ __launch_bounds__(256) void k_finalize(const float* __restrict__ partial,
                                                  const float* __restrict__ bias,
                                                  const int* __restrict__ x,
                                                  float* __restrict__ out) {
    int b = blockIdx.x;
    int tid = threadIdx.x;
    int ji = tid & 15, ci = tid >> 4;
    int jo = b * 16 + ji;
    float sum = 0.f;
#pragma unroll 8
    for (int c = ci; c < NMM; c += 16)
        sum += partial[(size_t)c * 1024 + jo];
    __shared__ float red[16][17];
    __shared__ float lg[16];
    __shared__ int sidx[32];
    red[ci][ji] = sum;
    if (tid < 32) {
        const int* xb = x + (size_t)tid * (16384 * 4);
        sidx[tid] = 8 * xb[0] + 4 * xb[1] + 2 * xb[2] + xb[3];
    }
    __syncthreads();
    if (ci == 0) {
        float s = 0.f;
#pragma unroll
        for (int k = 0; k < 16; ++k) s += red[k][ji];
        lg[ji] = s + bias[jo & 63];
    }
    __syncthreads();
    int myidx = b >> 2, o0 = (b & 3) * 16;
#pragma unroll
    for (int r = 0; r < 2; ++r) {
        int slot = tid + 256 * r;          // 512 slots = 32 batches x 16 o's
        int bb = slot >> 4, k = slot & 15;
        if (sidx[bb] == myidx) {
            float z = lg[k];
            out[bb * 64 + o0 + k] = 1.f / (1.f + expf(-z));
        }
    }
}

extern "C" void kernel_launch(void* const* d_in, const int* in_sizes, int n_in,
                              void* d_out, int out_size, void* d_ws, size_t ws_size,
                              hipStream_t stream) {
    const int*   x    = (const int*)d_in[0];
    const float* qw   = (const float*)d_in[1];
    const float* W    = (const float*)d_in[2];
    const float* bias = (const float*)d_in[3];
    float* out = (float*)d_out;

    char* ws = (char*)d_ws;
    float2*   buf0    = (float2*)(ws + (1ull << 20));      // 2 MB
    float2*   buf1    = (float2*)(ws + (4ull << 20));      // 2 MB
    float*    probs   = (float*)(ws + (8ull << 20));       // 1 MB
    float*    partial = (float*)(ws + (12ull << 20));      // 4 MB

    kInit<<<256, 256, 0, stream>>>(buf0, qw);                       // L0 + L1 low
    kBC  <<<256, 256, 0, stream>>>(buf0, buf1, nullptr, qw, 1);     // L1 high + P
    kA   <<<256, 256, 0, stream>>>(buf1, qw, 2);
    kBC  <<<256, 256, 0, stream>>>(buf1, buf0, nullptr, qw, 2);
    kA   <<<256, 256, 0, stream>>>(buf0, qw, 3);
    kBC  <<<256, 256, 0, stream>>>(buf0, nullptr, probs, qw, 3);

    k_mm<<<NMM, 256, 0, stream>>>(probs, W, partial);
    k_finalize<<<64, 256, 0, stream>>>(partial, bias, x, out);
}

// Round 7
// 83.950 us; speedup vs baseline: 3.8918x; 3.8918x over previous
//
#include <hip/hip_runtime.h>
#include <math.h>

// QNN: all gates are GF(2)-convolutions and the CNOT cascade is a linear bit
// permutation P  =>  the 16 initial basis states evolve into XOR-translates
// of ONE simulated state: probs_j(i) = probs_0(i ^ P^4(j)).
// Simulate a single 2^18 complex state (2 MB), then
// logits[j][o] = sum_d probs_0(d ^ T_j) * W[o][d] + b[o];
// out[b][o] = sigmoid(logits[idx_b][o]).
//
// Bit convention: wire w <-> bit p = 17-w.  P: out bit q (q<=16) =
// parity(i>>q); out bit 17 = parity(i & 0x1FFFF).

#define DIM (1 << 18)
#define NW 18
#define CH 128                      // k_mm d-columns per block
#define NMM (DIM / CH)              // 2048 blocks

__device__ __forceinline__ unsigned perm18(unsigned i) {
    unsigned s = i;
    s ^= s >> 1; s ^= s >> 2; s ^= s >> 4; s ^= s >> 8; s ^= s >> 16;
    unsigned out = s & 0x1FFFFu;
    out |= ((s ^ (i >> 17)) & 1u) << 17;
    return out;
}

__device__ __forceinline__ unsigned pinv18(unsigned b) {
    unsigned t = b & 0x1FFFFu;                 // s_0..s_16
    unsigned u = (t ^ (t >> 1)) & 0xFFFFu;     // i_0..i_15
    unsigned i17 = ((b >> 17) ^ t) & 1u;
    unsigned i16 = ((t >> 16) ^ i17) & 1u;
    return u | (i16 << 16) | (i17 << 17);
}

__device__ __forceinline__ void bfly(float2& a0, float2& a1, float c, float s) {
    float2 n0 = make_float2(c * a0.x + s * a1.y, c * a0.y - s * a1.x);
    float2 n1 = make_float2(c * a1.x + s * a0.y, c * a1.y - s * a0.x);
    a0 = n0; a1 = n1;
}

// ---- kInit: analytic layer-0 (post-P basis) + layer-1 gates bits 0..9 ------
__global__ __launch_bounds__(256) void kInit(float2* buf, const float* qw) {
    __shared__ float2 t[1024];
    __shared__ float2 gsh[10];
    int tid = threadIdx.x;
    if (tid < 10) {
        float th = qw[1 * NW + (17 - tid)] * 0.5f;
        gsh[tid] = make_float2(cosf(th), sinf(th));
    }
    float c[NW], s[NW];
#pragma unroll
    for (int w = 0; w < NW; ++w) {
        float th = qw[w] * 0.5f;
        c[w] = cosf(th); s[w] = sinf(th);
    }
    unsigned base = blockIdx.x * 1024u;
#pragma unroll
    for (int r = 0; r < 4; ++r) {
        int k = tid + r * 256;
        unsigned i = pinv18(base + k);
        float m = 1.0f;
#pragma unroll
        for (int p = 0; p < 18; ++p)
            m *= ((i >> p) & 1u) ? s[17 - p] : c[17 - p];
        int k4 = __popc(i) & 3;
        float2 a;
        if      (k4 == 0) a = make_float2( m, 0.f);
        else if (k4 == 1) a = make_float2(0.f, -m);
        else if (k4 == 2) a = make_float2(-m, 0.f);
        else              a = make_float2(0.f,  m);
        t[k] = a;
    }
    __syncthreads();
    for (int p = 0; p <= 9; ++p) {
        float2 g = gsh[p];
        int mlow = (1 << p) - 1;
        for (int k = tid; k < 512; k += 256) {
            int i0 = ((k >> p) << (p + 1)) | (k & mlow);
            int i1 = i0 | (1 << p);
            bfly(t[i0], t[i1], g.x, g.y);
        }
        __syncthreads();
    }
#pragma unroll
    for (int r = 0; r < 4; ++r) {
        int k = tid + r * 256;
        buf[base + k] = t[k];
    }
}

// ---- kA: 10 RX gates on bits 0..9, in-place, contiguous 1024 tiles ---------
__global__ __launch_bounds__(256) void kA(float2* buf, const float* qw, int layer) {
    __shared__ float2 t[1024];
    __shared__ float2 gsh[10];
    int tid = threadIdx.x;
    if (tid < 10) {
        float th = qw[layer * NW + (17 - tid)] * 0.5f;
        gsh[tid] = make_float2(cosf(th), sinf(th));
    }
    unsigned base = blockIdx.x * 1024u;
#pragma unroll
    for (int r = 0; r < 4; ++r) t[tid + r * 256] = buf[base + tid + r * 256];
    __syncthreads();
    for (int p = 0; p <= 9; ++p) {
        float2 g = gsh[p];
        int mlow = (1 << p) - 1;
        for (int k = tid; k < 512; k += 256) {
            int i0 = ((k >> p) << (p + 1)) | (k & mlow);
            int i1 = i0 | (1 << p);
            bfly(t[i0], t[i1], g.x, g.y);
        }
        __syncthreads();
    }
#pragma unroll
    for (int r = 0; r < 4; ++r) buf[base + tid + r * 256] = t[tid + r * 256];
}

// ---- kBC: 8 RX gates on bits 10..17 + perm P scatter -----------------------
// tile: h in [0,256) = bits 10..17, lo in [0,4) = bits 0..1; block = bits 2..9.
// If probs != nullptr, emit |amp|^2 (final layer).
__global__ __launch_bounds__(256) void kBC(const float2* __restrict__ in, float2* out,
                                           float* probs, const float* qw, int layer) {
    __shared__ float2 t[1024];
    __shared__ float2 gsh[8];
    int tid = threadIdx.x;
    if (tid < 8) {                              // bit 10+q -> wire 7-q
        float th = qw[layer * NW + (7 - tid)] * 0.5f;
        gsh[tid] = make_float2(cosf(th), sinf(th));
    }
    unsigned m = blockIdx.x;                    // bits 2..9
#pragma unroll
    for (int r = 0; r < 4; ++r) {
        int k = tid + r * 256;
        int h = k >> 2, lo = k & 3;
        t[k] = in[((unsigned)h << 10) | (m << 2) | lo];
    }
    __syncthreads();
    for (int q = 0; q <= 7; ++q) {
        float2 g = gsh[q];
        int mq = (1 << q) - 1;
        for (int k = tid; k < 512; k += 256) {
            int hh = k >> 2, lo = k & 3;
            int h0 = ((hh >> q) << (q + 1)) | (hh & mq);
            int h1 = h0 | (1 << q);
            bfly(t[(h0 << 2) | lo], t[(h1 << 2) | lo], g.x, g.y);
        }
        __syncthreads();
    }
    if (probs) {
#pragma unroll
        for (int r = 0; r < 4; ++r) {
            int k = tid + r * 256;
            int h = k >> 2, lo = k & 3;
            unsigned i = ((unsigned)h << 10) | (m << 2) | lo;
            float2 a = t[k];
            probs[perm18(i)] = a.x * a.x + a.y * a.y;
        }
    } else {
#pragma unroll
        for (int r = 0; r < 4; ++r) {
            int k = tid + r * 256;
            int h = k >> 2, lo = k & 3;
            unsigned i = ((unsigned)h << 10) | (m << 2) | lo;
            out[perm18(i)] = t[k];
        }
    }
}

// ---- logits partials: 2048 blocks, single CH=128 stage, 4j x 4o tile -------
// thread = (dq:2 | jg:2 | og:4); j = jg*4+u, o = og + 16*v.
__global__ __launch_bounds__(256) void k_mm(const float* __restrict__ p0,
                                            const float* __restrict__ W,
                                            float* __restrict__ partial) {
    __shared__ float Wl[64][132];
    __shared__ float Pl[16][132];
    __shared__ unsigned Tsh[16];
    int tid = threadIdx.x;
    if (tid < 16) {
        unsigned v = (unsigned)tid;
#pragma unroll
        for (int r = 0; r < 4; ++r) v = perm18(v);
        Tsh[tid] = v;
    }
    __syncthreads();
    unsigned d0 = (unsigned)blockIdx.x * CH;

    // stage W: 64 rows x 128 cols, float4 coalesced
    for (int k = tid; k < 64 * (CH / 4); k += 256) {
        int o = k >> 5, c4 = (k & 31) * 4;
        *(float4*)&Wl[o][c4] = *(const float4*)&W[(size_t)o * DIM + d0 + c4];
    }
    // stage P translated: Pl[j][m ^ (Tj&127)] = p0[(d0 ^ (Tj&~127)) + m]
    for (int k = tid; k < 16 * CH; k += 256) {
        int j = k >> 7, m = k & 127;
        unsigned Tj = Tsh[j];
        Pl[j][m ^ (Tj & 127u)] = p0[(d0 ^ (Tj & ~127u)) + m];
    }
    __syncthreads();

    int dq = tid >> 6, jg = (tid >> 4) & 3, og = tid & 15;
    float acc[4][4] = {};
#pragma unroll
    for (int it = 0; it < 8; ++it) {
        int d = dq * 32 + it * 4;
        float4 pv[4], wv[4];
#pragma unroll
        for (int u = 0; u < 4; ++u) pv[u] = *(const float4*)&Pl[jg * 4 + u][d];
#pragma unroll
        for (int v = 0; v < 4; ++v) wv[v] = *(const float4*)&Wl[og + 16 * v][d];
#pragma unroll
        for (int u = 0; u < 4; ++u)
#pragma unroll
            for (int v = 0; v < 4; ++v)
                acc[u][v] += pv[u].x * wv[v].x + pv[u].y * wv[v].y
                           + pv[u].z * wv[v].z + pv[u].w * wv[v].w;
    }
    __syncthreads();

    // reduce the 4 dq groups (reuse Wl as 16 KB scratch)
    float* red = &Wl[0][0];
#pragma unroll
    for (int u = 0; u < 4; ++u)
#pragma unroll
        for (int v = 0; v < 4; ++v)
            red[(u * 4 + v) * 256 + tid] = acc[u][v];
    __syncthreads();
    if (tid < 64) {
        int jg2 = tid >> 4, og2 = tid & 15;
#pragma unroll
        for (int u = 0; u < 4; ++u)
#pragma unroll
            for (int v = 0; v < 4; ++v) {
                int idx = u * 4 + v;
                float ssum = red[idx * 256 + tid] + red[idx * 256 + 64 + tid]
                           + red[idx * 256 + 128 + tid] + red[idx * 256 + 192 + tid];
                partial[(size_t)blockIdx.x * 1024 + (jg2 * 4 + u) * 64 + og2 + 16 * v] = ssum;
            }
    }
}

// ---- finalize: reduce partials -> logits; per-batch lookup + sigmoid -------
// 64 blocks; block b owns idx = b>>2, o in [(b&3)*16, +16).
__global__ __launch_bounds__(256) void k_finalize(const float* __restrict__ partial,
                                                  const float* __restrict__ bias,
                                                  const int* __restrict__ x,
                                                  float* __restrict__ out) {
    int b = blockIdx.x;
    int tid = threadIdx.x;
    int ji = tid & 15, ci = tid >> 4;
    int jo = b * 16 + ji;
    float sum = 0.f;
#pragma unroll 8
    for (int c = ci; c < NMM; c += 16)
        sum += partial[(size_t)c * 1024 + jo];
    __shared__ float red[16][17];
    __shared__ float lg[16];
    __shared__ int sidx[32];
    red[ci][ji] = sum;
    if (tid < 32) {
        const int* xb = x + (size_t)tid * (16384 * 4);
        sidx[tid] = 8 * xb[0] + 4 * xb[1] + 2 * xb[2] + xb[3];
    }
    __syncthreads();
    if (ci == 0) {
        float s = 0.f;
#pragma unroll
        for (int k = 0; k < 16; ++k) s += red[k][ji];
        lg[ji] = s + bias[jo & 63];
    }
    __syncthreads();
    int myidx = b >> 2, o0 = (b & 3) * 16;
#pragma unroll
    for (int r = 0; r < 2; ++r) {
        int slot = tid + 256 * r;          // 512 slots = 32 batches x 16 o's
        int bb = slot >> 4, k = slot & 15;
        if (sidx[bb] == myidx) {
            float z = lg[k];
            out[bb * 64 + o0 + k] = 1.f / (1.f + expf(-z));
        }
    }
}

extern "C" void kernel_launch(void* const* d_in, const int* in_sizes, int n_in,
                              void* d_out, int out_size, void* d_ws, size_t ws_size,
                              hipStream_t stream) {
    const int*   x    = (const int*)d_in[0];
    const float* qw   = (const float*)d_in[1];
    const float* W    = (const float*)d_in[2];
    const float* bias = (const float*)d_in[3];
    float* out = (float*)d_out;

    char* ws = (char*)d_ws;
    float2*   buf0    = (float2*)(ws + (1ull << 20));      // 2 MB
    float2*   buf1    = (float2*)(ws + (4ull << 20));      // 2 MB
    float*    probs   = (float*)(ws + (8ull << 20));       // 1 MB
    float*    partial = (float*)(ws + (16ull << 20));      // 8 MB

    kInit<<<256, 256, 0, stream>>>(buf0, qw);                       // L0 + L1 low
    kBC  <<<256, 256, 0, stream>>>(buf0, buf1, nullptr, qw, 1);     // L1 high + P
    kA   <<<256, 256, 0, stream>>>(buf1, qw, 2);
    kBC  <<<256, 256, 0, stream>>>(buf1, buf0, nullptr, qw, 2);
    kA   <<<256, 256, 0, stream>>>(buf0, qw, 3);
    kBC  <<<256, 256, 0, stream>>>(buf0, nullptr, probs, qw, 3);

    k_mm<<<NMM, 256, 0, stream>>>(probs, W, partial);
    k_finalize<<<64, 256, 0, stream>>>(partial, bias, x, out);
}

// Round 8
// 79.175 us; speedup vs baseline: 4.1265x; 1.0603x over previous
//
#include <hip/hip_runtime.h>
#include <math.h>

// QNN: all gates are GF(2)-convolutions and the CNOT cascade is a linear bit
// permutation P  =>  the 16 initial basis states evolve into XOR-translates
// of ONE simulated state: probs_j(i) = probs_0(i ^ P^4(j)).
// Simulate a single 2^18 complex state (2 MB), then
// logits[j][o] = sum_d probs_0(d ^ T_j) * W[o][d] + b[o];
// out[b][o] = sigmoid(logits[idx_b][o]).
//
// Bit convention: wire w <-> bit p = 17-w.  P: out bit q (q<=16) =
// parity(i>>q); out bit 17 = parity(i & 0x1FFFF).

#define DIM (1 << 18)
#define NW 18
#define CH 128                      // k_mm d-columns per LDS stage
#define CPB 2                       // chunks per k_mm block
#define NMM (DIM / (CH * CPB))      // 1024 blocks

__device__ __forceinline__ unsigned perm18(unsigned i) {
    unsigned s = i;
    s ^= s >> 1; s ^= s >> 2; s ^= s >> 4; s ^= s >> 8; s ^= s >> 16;
    unsigned out = s & 0x1FFFFu;
    out |= ((s ^ (i >> 17)) & 1u) << 17;
    return out;
}

__device__ __forceinline__ unsigned pinv18(unsigned b) {
    unsigned t = b & 0x1FFFFu;                 // s_0..s_16
    unsigned u = (t ^ (t >> 1)) & 0xFFFFu;     // i_0..i_15
    unsigned i17 = ((b >> 17) ^ t) & 1u;
    unsigned i16 = ((t >> 16) ^ i17) & 1u;
    return u | (i16 << 16) | (i17 << 17);
}

__device__ __forceinline__ void bfly(float2& a0, float2& a1, float c, float s) {
    float2 n0 = make_float2(c * a0.x + s * a1.y, c * a0.y - s * a1.x);
    float2 n1 = make_float2(c * a1.x + s * a0.y, c * a1.y - s * a0.x);
    a0 = n0; a1 = n1;
}

// ---- kInit: analytic layer-0 (post-P basis) + layer-1 gates bits 0..9 ------
__global__ __launch_bounds__(256) void kInit(float2* buf, const float* qw) {
    __shared__ float2 t[1024];
    __shared__ float2 gsh[10];
    int tid = threadIdx.x;
    if (tid < 10) {
        float th = qw[1 * NW + (17 - tid)] * 0.5f;
        gsh[tid] = make_float2(cosf(th), sinf(th));
    }
    float c[NW], s[NW];
#pragma unroll
    for (int w = 0; w < NW; ++w) {
        float th = qw[w] * 0.5f;
        c[w] = cosf(th); s[w] = sinf(th);
    }
    unsigned base = blockIdx.x * 1024u;
#pragma unroll
    for (int r = 0; r < 4; ++r) {
        int k = tid + r * 256;
        unsigned i = pinv18(base + k);
        float m = 1.0f;
#pragma unroll
        for (int p = 0; p < 18; ++p)
            m *= ((i >> p) & 1u) ? s[17 - p] : c[17 - p];
        int k4 = __popc(i) & 3;
        float2 a;
        if      (k4 == 0) a = make_float2( m, 0.f);
        else if (k4 == 1) a = make_float2(0.f, -m);
        else if (k4 == 2) a = make_float2(-m, 0.f);
        else              a = make_float2(0.f,  m);
        t[k] = a;
    }
    __syncthreads();
    for (int p = 0; p <= 9; ++p) {
        float2 g = gsh[p];
        int mlow = (1 << p) - 1;
        for (int k = tid; k < 512; k += 256) {
            int i0 = ((k >> p) << (p + 1)) | (k & mlow);
            int i1 = i0 | (1 << p);
            bfly(t[i0], t[i1], g.x, g.y);
        }
        __syncthreads();
    }
#pragma unroll
    for (int r = 0; r < 4; ++r) {
        int k = tid + r * 256;
        buf[base + k] = t[k];
    }
}

// ---- kA: 10 RX gates on bits 0..9, in-place, contiguous 1024 tiles ---------
__global__ __launch_bounds__(256) void kA(float2* buf, const float* qw, int layer) {
    __shared__ float2 t[1024];
    __shared__ float2 gsh[10];
    int tid = threadIdx.x;
    if (tid < 10) {
        float th = qw[layer * NW + (17 - tid)] * 0.5f;
        gsh[tid] = make_float2(cosf(th), sinf(th));
    }
    unsigned base = blockIdx.x * 1024u;
#pragma unroll
    for (int r = 0; r < 4; ++r) t[tid + r * 256] = buf[base + tid + r * 256];
    __syncthreads();
    for (int p = 0; p <= 9; ++p) {
        float2 g = gsh[p];
        int mlow = (1 << p) - 1;
        for (int k = tid; k < 512; k += 256) {
            int i0 = ((k >> p) << (p + 1)) | (k & mlow);
            int i1 = i0 | (1 << p);
            bfly(t[i0], t[i1], g.x, g.y);
        }
        __syncthreads();
    }
#pragma unroll
    for (int r = 0; r < 4; ++r) buf[base + tid + r * 256] = t[tid + r * 256];
}

// ---- kBC: 8 RX gates on bits 10..17 + perm P scatter -----------------------
// tile: h in [0,256) = bits 10..17, lo in [0,4) = bits 0..1; block = bits 2..9.
// If probs != nullptr, emit |amp|^2 (final layer).
__global__ __launch_bounds__(256) void kBC(const float2* __restrict__ in, float2* out,
                                           float* probs, const float* qw, int layer) {
    __shared__ float2 t[1024];
    __shared__ float2 gsh[8];
    int tid = threadIdx.x;
    if (tid < 8) {                              // bit 10+q -> wire 7-q
        float th = qw[layer * NW + (7 - tid)] * 0.5f;
        gsh[tid] = make_float2(cosf(th), sinf(th));
    }
    unsigned m = blockIdx.x;                    // bits 2..9
#pragma unroll
    for (int r = 0; r < 4; ++r) {
        int k = tid + r * 256;
        int h = k >> 2, lo = k & 3;
        t[k] = in[((unsigned)h << 10) | (m << 2) | lo];
    }
    __syncthreads();
    for (int q = 0; q <= 7; ++q) {
        float2 g = gsh[q];
        int mq = (1 << q) - 1;
        for (int k = tid; k < 512; k += 256) {
            int hh = k >> 2, lo = k & 3;
            int h0 = ((hh >> q) << (q + 1)) | (hh & mq);
            int h1 = h0 | (1 << q);
            bfly(t[(h0 << 2) | lo], t[(h1 << 2) | lo], g.x, g.y);
        }
        __syncthreads();
    }
    if (probs) {
#pragma unroll
        for (int r = 0; r < 4; ++r) {
            int k = tid + r * 256;
            int h = k >> 2, lo = k & 3;
            unsigned i = ((unsigned)h << 10) | (m << 2) | lo;
            float2 a = t[k];
            probs[perm18(i)] = a.x * a.x + a.y * a.y;
        }
    } else {
#pragma unroll
        for (int r = 0; r < 4; ++r) {
            int k = tid + r * 256;
            int h = k >> 2, lo = k & 3;
            unsigned i = ((unsigned)h << 10) | (m << 2) | lo;
            out[perm18(i)] = t[k];
        }
    }
}

// ---- logits partials: 1024 blocks x 2 chunks, named-reg prefetch -----------
// thread = (dq:2 | jg:2 | og:4); j = jg*4+u, o = og + 16*v.
__global__ __launch_bounds__(256) void k_mm(const float* __restrict__ p0,
                                            const float* __restrict__ W,
                                            float* __restrict__ partial) {
    __shared__ float Wl[64][132];
    __shared__ float Pl[16][132];
    __shared__ unsigned Tsh[16];
    int tid = threadIdx.x;
    if (tid < 16) {
        unsigned v = (unsigned)tid;
#pragma unroll
        for (int r = 0; r < 4; ++r) v = perm18(v);
        Tsh[tid] = v;
    }
    __syncthreads();

    unsigned d00 = (unsigned)blockIdx.x * (CH * CPB);
    // staging geometry: W rows wrow+8t (8 float4), p0 rows prow+2t (8 floats)
    int wrow = tid >> 5;                   // 0..7
    int wcol = (tid & 31) * 4;
    int prow = tid >> 7;                   // 0..1
    int pcol = tid & 127;
    unsigned Tp[8];
#pragma unroll
    for (int t = 0; t < 8; ++t) Tp[t] = Tsh[prow + 2 * t];

    int dq = tid >> 6, jg = (tid >> 4) & 3, og = tid & 15;
    float acc[4][4] = {};

    // ---- stage chunk 0 directly into LDS ----
    {
        unsigned d0 = d00;
#pragma unroll
        for (int t = 0; t < 8; ++t)
            *(float4*)&Wl[wrow + 8 * t][wcol] =
                *(const float4*)&W[(size_t)(wrow + 8 * t) * DIM + d0 + wcol];
#pragma unroll
        for (int t = 0; t < 8; ++t)
            Pl[prow + 2 * t][pcol ^ (Tp[t] & 127u)] = p0[(d0 ^ (Tp[t] & ~127u)) + pcol];
    }
    __syncthreads();

    // ---- issue chunk 1 global loads into named regs (hide under compute) ----
    float4 wr[8];
    float  pr[8];
    {
        unsigned d1 = d00 + CH;
#pragma unroll
        for (int t = 0; t < 8; ++t)
            wr[t] = *(const float4*)&W[(size_t)(wrow + 8 * t) * DIM + d1 + wcol];
#pragma unroll
        for (int t = 0; t < 8; ++t)
            pr[t] = p0[(d1 ^ (Tp[t] & ~127u)) + pcol];
    }

    // ---- compute chunk 0 ----
#pragma unroll
    for (int it = 0; it < 8; ++it) {
        int d = dq * 32 + it * 4;
        float4 pv[4], wv[4];
#pragma unroll
        for (int u = 0; u < 4; ++u) pv[u] = *(const float4*)&Pl[jg * 4 + u][d];
#pragma unroll
        for (int v = 0; v < 4; ++v) wv[v] = *(const float4*)&Wl[og + 16 * v][d];
#pragma unroll
        for (int u = 0; u < 4; ++u)
#pragma unroll
            for (int v = 0; v < 4; ++v)
                acc[u][v] += pv[u].x * wv[v].x + pv[u].y * wv[v].y
                           + pv[u].z * wv[v].z + pv[u].w * wv[v].w;
    }
    __syncthreads();

    // ---- commit chunk 1 regs -> LDS ----
#pragma unroll
    for (int t = 0; t < 8; ++t)
        *(float4*)&Wl[wrow + 8 * t][wcol] = wr[t];
#pragma unroll
    for (int t = 0; t < 8; ++t)
        Pl[prow + 2 * t][pcol ^ (Tp[t] & 127u)] = pr[t];
    __syncthreads();

    // ---- compute chunk 1 ----
#pragma unroll
    for (int it = 0; it < 8; ++it) {
        int d = dq * 32 + it * 4;
        float4 pv[4], wv[4];
#pragma unroll
        for (int u = 0; u < 4; ++u) pv[u] = *(const float4*)&Pl[jg * 4 + u][d];
#pragma unroll
        for (int v = 0; v < 4; ++v) wv[v] = *(const float4*)&Wl[og + 16 * v][d];
#pragma unroll
        for (int u = 0; u < 4; ++u)
#pragma unroll
            for (int v = 0; v < 4; ++v)
                acc[u][v] += pv[u].x * wv[v].x + pv[u].y * wv[v].y
                           + pv[u].z * wv[v].z + pv[u].w * wv[v].w;
    }
    __syncthreads();

    // ---- reduce the 4 dq groups (reuse Wl as 16 KB scratch) ----
    float* red = &Wl[0][0];
#pragma unroll
    for (int u = 0; u < 4; ++u)
#pragma unroll
        for (int v = 0; v < 4; ++v)
            red[(u * 4 + v) * 256 + tid] = acc[u][v];
    __syncthreads();
    if (tid < 64) {
        int jg2 = tid >> 4, og2 = tid & 15;
#pragma unroll
        for (int u = 0; u < 4; ++u)
#pragma unroll
            for (int v = 0; v < 4; ++v) {
                int idx = u * 4 + v;
                float ssum = red[idx * 256 + tid] + red[idx * 256 + 64 + tid]
                           + red[idx * 256 + 128 + tid] + red[idx * 256 + 192 + tid];
                partial[(size_t)blockIdx.x * 1024 + (jg2 * 4 + u) * 64 + og2 + 16 * v] = ssum;
            }
    }
}

// ---- finalize: reduce partials -> logits; per-batch lookup + sigmoid -------
// 64 blocks; block b owns idx = b>>2, o in [(b&3)*16, +16).
__global__ __launch_bounds__(256) void k_finalize(const float* __restrict__ partial,
                                                  const float* __restrict__ bias,
                                                  const int* __restrict__ x,
                                                  float* __restrict__ out) {
    int b = blockIdx.x;
    int tid = threadIdx.x;
    int ji = tid & 15, ci = tid >> 4;
    int jo = b * 16 + ji;
    float sum = 0.f;
#pragma unroll 8
    for (int c = ci; c < NMM; c += 16)
        sum += partial[(size_t)c * 1024 + jo];
    __shared__ float red[16][17];
    __shared__ float lg[16];
    __shared__ int sidx[32];
    red[ci][ji] = sum;
    if (tid < 32) {
        const int* xb = x + (size_t)tid * (16384 * 4);
        sidx[tid] = 8 * xb[0] + 4 * xb[1] + 2 * xb[2] + xb[3];
    }
    __syncthreads();
    if (ci == 0) {
        float s = 0.f;
#pragma unroll
        for (int k = 0; k < 16; ++k) s += red[k][ji];
        lg[ji] = s + bias[jo & 63];
    }
    __syncthreads();
    int myidx = b >> 2, o0 = (b & 3) * 16;
#pragma unroll
    for (int r = 0; r < 2; ++r) {
        int slot = tid + 256 * r;          // 512 slots = 32 batches x 16 o's
        int bb = slot >> 4, k = slot & 15;
        if (sidx[bb] == myidx) {
            float z = lg[k];
            out[bb * 64 + o0 + k] = 1.f / (1.f + expf(-z));
        }
    }
}

extern "C" void kernel_launch(void* const* d_in, const int* in_sizes, int n_in,
                              void* d_out, int out_size, void* d_ws, size_t ws_size,
                              hipStream_t stream) {
    const int*   x    = (const int*)d_in[0];
    const float* qw   = (const float*)d_in[1];
    const float* W    = (const float*)d_in[2];
    const float* bias = (const float*)d_in[3];
    float* out = (float*)d_out;

    char* ws = (char*)d_ws;
    float2*   buf0    = (float2*)(ws + (1ull << 20));      // 2 MB
    float2*   buf1    = (float2*)(ws + (4ull << 20));      // 2 MB
    float*    probs   = (float*)(ws + (8ull << 20));       // 1 MB
    float*    partial = (float*)(ws + (16ull << 20));      // 4 MB

    kInit<<<256, 256, 0, stream>>>(buf0, qw);                       // L0 + L1 low
    kBC  <<<256, 256, 0, stream>>>(buf0, buf1, nullptr, qw, 1);     // L1 high + P
    kA   <<<256, 256, 0, stream>>>(buf1, qw, 2);
    kBC  <<<256, 256, 0, stream>>>(buf1, buf0, nullptr, qw, 2);
    kA   <<<256, 256, 0, stream>>>(buf0, qw, 3);
    kBC  <<<256, 256, 0, stream>>>(buf0, nullptr, probs, qw, 3);

    k_mm<<<NMM, 256, 0, stream>>>(probs, W, partial);
    k_finalize<<<64, 256, 0, stream>>>(partial, bias, x, out);
}

// Round 9
// 65.511 us; speedup vs baseline: 4.9872x; 1.2086x over previous
//
#include <hip/hip_runtime.h>
#include <math.h>

// QNN: all gates are GF(2)-convolutions and the CNOT cascade is a linear bit
// permutation P  =>  the 16 initial basis states evolve into XOR-translates
// of ONE simulated state: probs_j(i) = probs_0(i ^ P^4(j)).
// Simulate a single 2^18 complex state (2 MB), then
// logits[j][o] = sum_d probs_0(d ^ T_j) * W[o][d] + b[o];  (MFMA, bf16 inputs)
// out[b][o] = sigmoid(logits[idx_b][o]).
//
// Bit convention: wire w <-> bit p = 17-w.  P: out bit q (q<=16) =
// parity(i>>q); out bit 17 = parity(i & 0x1FFFF).

#define DIM (1 << 18)
#define NW 18
#define CH 128                      // k_mm d-columns per LDS stage
#define CPB 2                       // chunks per k_mm block
#define NMM (DIM / (CH * CPB))      // 1024 blocks

typedef short short8 __attribute__((ext_vector_type(8)));   // 8 bf16 (4 VGPRs)
typedef float f32x4  __attribute__((ext_vector_type(4)));   // MFMA accumulator

__device__ __forceinline__ unsigned perm18(unsigned i) {
    unsigned s = i;
    s ^= s >> 1; s ^= s >> 2; s ^= s >> 4; s ^= s >> 8; s ^= s >> 16;
    unsigned out = s & 0x1FFFFu;
    out |= ((s ^ (i >> 17)) & 1u) << 17;
    return out;
}

__device__ __forceinline__ unsigned pinv18(unsigned b) {
    unsigned t = b & 0x1FFFFu;                 // s_0..s_16
    unsigned u = (t ^ (t >> 1)) & 0xFFFFu;     // i_0..i_15
    unsigned i17 = ((b >> 17) ^ t) & 1u;
    unsigned i16 = ((t >> 16) ^ i17) & 1u;
    return u | (i16 << 16) | (i17 << 17);
}

__device__ __forceinline__ void bfly(float2& a0, float2& a1, float c, float s) {
    float2 n0 = make_float2(c * a0.x + s * a1.y, c * a0.y - s * a1.x);
    float2 n1 = make_float2(c * a1.x + s * a0.y, c * a1.y - s * a0.x);
    a0 = n0; a1 = n1;
}

__device__ __forceinline__ short f2bf(float x) {            // RNE fp32->bf16
    unsigned u = __float_as_uint(x);
    return (short)((u + 0x7FFFu + ((u >> 16) & 1u)) >> 16);
}

// ---- kInit: analytic layer-0 (post-P basis) + layer-1 gates bits 0..9 ------
__global__ __launch_bounds__(256) void kInit(float2* buf, const float* qw) {
    __shared__ float2 t[1024];
    __shared__ float2 gsh[10];
    int tid = threadIdx.x;
    if (tid < 10) {
        float th = qw[1 * NW + (17 - tid)] * 0.5f;
        gsh[tid] = make_float2(cosf(th), sinf(th));
    }
    float c[NW], s[NW];
#pragma unroll
    for (int w = 0; w < NW; ++w) {
        float th = qw[w] * 0.5f;
        c[w] = cosf(th); s[w] = sinf(th);
    }
    unsigned base = blockIdx.x * 1024u;
#pragma unroll
    for (int r = 0; r < 4; ++r) {
        int k = tid + r * 256;
        unsigned i = pinv18(base + k);
        float m = 1.0f;
#pragma unroll
        for (int p = 0; p < 18; ++p)
            m *= ((i >> p) & 1u) ? s[17 - p] : c[17 - p];
        int k4 = __popc(i) & 3;
        float2 a;
        if      (k4 == 0) a = make_float2( m, 0.f);
        else if (k4 == 1) a = make_float2(0.f, -m);
        else if (k4 == 2) a = make_float2(-m, 0.f);
        else              a = make_float2(0.f,  m);
        t[k] = a;
    }
    __syncthreads();
    for (int p = 0; p <= 9; ++p) {
        float2 g = gsh[p];
        int mlow = (1 << p) - 1;
        for (int k = tid; k < 512; k += 256) {
            int i0 = ((k >> p) << (p + 1)) | (k & mlow);
            int i1 = i0 | (1 << p);
            bfly(t[i0], t[i1], g.x, g.y);
        }
        __syncthreads();
    }
#pragma unroll
    for (int r = 0; r < 4; ++r) {
        int k = tid + r * 256;
        buf[base + k] = t[k];
    }
}

// ---- kA: 10 RX gates on bits 0..9, in-place, contiguous 1024 tiles ---------
__global__ __launch_bounds__(256) void kA(float2* buf, const float* qw, int layer) {
    __shared__ float2 t[1024];
    __shared__ float2 gsh[10];
    int tid = threadIdx.x;
    if (tid < 10) {
        float th = qw[layer * NW + (17 - tid)] * 0.5f;
        gsh[tid] = make_float2(cosf(th), sinf(th));
    }
    unsigned base = blockIdx.x * 1024u;
#pragma unroll
    for (int r = 0; r < 4; ++r) t[tid + r * 256] = buf[base + tid + r * 256];
    __syncthreads();
    for (int p = 0; p <= 9; ++p) {
        float2 g = gsh[p];
        int mlow = (1 << p) - 1;
        for (int k = tid; k < 512; k += 256) {
            int i0 = ((k >> p) << (p + 1)) | (k & mlow);
            int i1 = i0 | (1 << p);
            bfly(t[i0], t[i1], g.x, g.y);
        }
        __syncthreads();
    }
#pragma unroll
    for (int r = 0; r < 4; ++r) buf[base + tid + r * 256] = t[tid + r * 256];
}

// ---- kBC: 8 RX gates on bits 10..17 + perm P scatter -----------------------
// tile: h in [0,256) = bits 10..17, lo in [0,4) = bits 0..1; block = bits 2..9.
// If probs != nullptr, emit |amp|^2 (final layer).
__global__ __launch_bounds__(256) void kBC(const float2* __restrict__ in, float2* out,
                                           float* probs, const float* qw, int layer) {
    __shared__ float2 t[1024];
    __shared__ float2 gsh[8];
    int tid = threadIdx.x;
    if (tid < 8) {                              // bit 10+q -> wire 7-q
        float th = qw[layer * NW + (7 - tid)] * 0.5f;
        gsh[tid] = make_float2(cosf(th), sinf(th));
    }
    unsigned m = blockIdx.x;                    // bits 2..9
#pragma unroll
    for (int r = 0; r < 4; ++r) {
        int k = tid + r * 256;
        int h = k >> 2, lo = k & 3;
        t[k] = in[((unsigned)h << 10) | (m << 2) | lo];
    }
    __syncthreads();
    for (int q = 0; q <= 7; ++q) {
        float2 g = gsh[q];
        int mq = (1 << q) - 1;
        for (int k = tid; k < 512; k += 256) {
            int hh = k >> 2, lo = k & 3;
            int h0 = ((hh >> q) << (q + 1)) | (hh & mq);
            int h1 = h0 | (1 << q);
            bfly(t[(h0 << 2) | lo], t[(h1 << 2) | lo], g.x, g.y);
        }
        __syncthreads();
    }
    if (probs) {
#pragma unroll
        for (int r = 0; r < 4; ++r) {
            int k = tid + r * 256;
            int h = k >> 2, lo = k & 3;
            unsigned i = ((unsigned)h << 10) | (m << 2) | lo;
            float2 a = t[k];
            probs[perm18(i)] = a.x * a.x + a.y * a.y;
        }
    } else {
#pragma unroll
        for (int r = 0; r < 4; ++r) {
            int k = tid + r * 256;
            int h = k >> 2, lo = k & 3;
            unsigned i = ((unsigned)h << 10) | (m << 2) | lo;
            out[perm18(i)] = t[k];
        }
    }
}

// ---- logits partials via MFMA: 1024 blocks x 2 chunks, reg prefetch --------
// 4 waves; wave w owns o-tile [16w,16w+16). Per chunk: 4x mfma_f32_16x16x32_bf16.
// A = probs-translate (16j x 32d), B = W (32d x 16o), both bf16 in LDS.
// Frag layout: A/B lane -> (row/col = lane&15, k = (lane>>4)*8 + t);
// C/D lane -> (row = (lane>>4)*4 + reg, col = lane&15).   [m89 convention]
__global__ __launch_bounds__(256) void k_mm(const float* __restrict__ p0,
                                            const float* __restrict__ W,
                                            float* __restrict__ partial) {
    __shared__ short Wl[64][136];       // bf16, pitch 272 B (17*16: aligned, 2-way banks)
    __shared__ short Pl[16][136];
    __shared__ unsigned Tsh[16];
    int tid = threadIdx.x;
    if (tid < 16) {
        unsigned v = (unsigned)tid;
#pragma unroll
        for (int r = 0; r < 4; ++r) v = perm18(v);
        Tsh[tid] = v;
    }
    __syncthreads();

    unsigned d00 = (unsigned)blockIdx.x * (CH * CPB);
    // staging geometry: W rows wrow+8t (float4 cols), p0 rows prow+2t
    int wrow = tid >> 5;                   // 0..7
    int wcol = (tid & 31) * 4;
    int prow = tid >> 7;                   // 0..1
    int pcol = tid & 127;
    unsigned Tp[8];
#pragma unroll
    for (int t = 0; t < 8; ++t) Tp[t] = Tsh[prow + 2 * t];

    int lane = tid & 63, wv = tid >> 6;    // wave -> o-tile 16*wv
    f32x4 acc = {0.f, 0.f, 0.f, 0.f};

    float4 wr[8];
    float  pr[8];

    // ---- stage chunk 0 directly into LDS (fp32 -> bf16 in-register) ----
#pragma unroll
    for (int t = 0; t < 8; ++t)
        wr[t] = *(const float4*)&W[(size_t)(wrow + 8 * t) * DIM + d00 + wcol];
#pragma unroll
    for (int t = 0; t < 8; ++t)
        pr[t] = p0[(d00 ^ (Tp[t] & ~127u)) + pcol];
#pragma unroll
    for (int t = 0; t < 8; ++t) {
        short4 b = make_short4(f2bf(wr[t].x), f2bf(wr[t].y), f2bf(wr[t].z), f2bf(wr[t].w));
        *(short4*)&Wl[wrow + 8 * t][wcol] = b;
    }
#pragma unroll
    for (int t = 0; t < 8; ++t)
        Pl[prow + 2 * t][pcol ^ (Tp[t] & 127u)] = f2bf(pr[t]);
    __syncthreads();

    // ---- issue chunk 1 global loads (hide under chunk-0 MFMAs) ----
    {
        unsigned d1 = d00 + CH;
#pragma unroll
        for (int t = 0; t < 8; ++t)
            wr[t] = *(const float4*)&W[(size_t)(wrow + 8 * t) * DIM + d1 + wcol];
#pragma unroll
        for (int t = 0; t < 8; ++t)
            pr[t] = p0[(d1 ^ (Tp[t] & ~127u)) + pcol];
    }

    // ---- compute chunk 0 ----
    int arow = lane & 15, kg = (lane >> 4) * 8;
#pragma unroll
    for (int kk = 0; kk < 4; ++kk) {
        short8 a = *(const short8*)&Pl[arow][kk * 32 + kg];
        short8 b = *(const short8*)&Wl[16 * wv + arow][kk * 32 + kg];
        acc = __builtin_amdgcn_mfma_f32_16x16x32_bf16(a, b, acc, 0, 0, 0);
    }
    __syncthreads();

    // ---- commit chunk 1 -> LDS ----
#pragma unroll
    for (int t = 0; t < 8; ++t) {
        short4 b = make_short4(f2bf(wr[t].x), f2bf(wr[t].y), f2bf(wr[t].z), f2bf(wr[t].w));
        *(short4*)&Wl[wrow + 8 * t][wcol] = b;
    }
#pragma unroll
    for (int t = 0; t < 8; ++t)
        Pl[prow + 2 * t][pcol ^ (Tp[t] & 127u)] = f2bf(pr[t]);
    __syncthreads();

    // ---- compute chunk 1 ----
#pragma unroll
    for (int kk = 0; kk < 4; ++kk) {
        short8 a = *(const short8*)&Pl[arow][kk * 32 + kg];
        short8 b = *(const short8*)&Wl[16 * wv + arow][kk * 32 + kg];
        acc = __builtin_amdgcn_mfma_f32_16x16x32_bf16(a, b, acc, 0, 0, 0);
    }

    // ---- write D: row j = (lane>>4)*4 + r, col o = 16*wv + (lane&15) ----
    float* dst = partial + (size_t)blockIdx.x * 1024;
#pragma unroll
    for (int r = 0; r < 4; ++r) {
        int jrow = (lane >> 4) * 4 + r;
        dst[jrow * 64 + 16 * wv + (lane & 15)] = acc[r];
    }
}

// ---- finalize: reduce partials -> logits; per-batch lookup + sigmoid -------
// 64 blocks; block b owns idx = b>>2, o in [(b&3)*16, +16).
__global__ __launch_bounds__(256) void k_finalize(const float* __restrict__ partial,
                                                  const float* __restrict__ bias,
                                                  const int* __restrict__ x,
                                                  float* __restrict__ out) {
    int b = blockIdx.x;
    int tid = threadIdx.x;
    int ji = tid & 15, ci = tid >> 4;
    int jo = b * 16 + ji;
    float sum = 0.f;
#pragma unroll 8
    for (int c = ci; c < NMM; c += 16)
        sum += partial[(size_t)c * 1024 + jo];
    __shared__ float red[16][17];
    __shared__ float lg[16];
    __shared__ int sidx[32];
    red[ci][ji] = sum;
    if (tid < 32) {
        const int* xb = x + (size_t)tid * (16384 * 4);
        sidx[tid] = 8 * xb[0] + 4 * xb[1] + 2 * xb[2] + xb[3];
    }
    __syncthreads();
    if (ci == 0) {
        float s = 0.f;
#pragma unroll
        for (int k = 0; k < 16; ++k) s += red[k][ji];
        lg[ji] = s + bias[jo & 63];
    }
    __syncthreads();
    int myidx = b >> 2, o0 = (b & 3) * 16;
#pragma unroll
    for (int r = 0; r < 2; ++r) {
        int slot = tid + 256 * r;          // 512 slots = 32 batches x 16 o's
        int bb = slot >> 4, k = slot & 15;
        if (sidx[bb] == myidx) {
            float z = lg[k];
            out[bb * 64 + o0 + k] = 1.f / (1.f + expf(-z));
        }
    }
}

extern "C" void kernel_launch(void* const* d_in, const int* in_sizes, int n_in,
                              void* d_out, int out_size, void* d_ws, size_t ws_size,
                              hipStream_t stream) {
    const int*   x    = (const int*)d_in[0];
    const float* qw   = (const float*)d_in[1];
    const float* W    = (const float*)d_in[2];
    const float* bias = (const float*)d_in[3];
    float* out = (float*)d_out;

    char* ws = (char*)d_ws;
    float2*   buf0    = (float2*)(ws + (1ull << 20));      // 2 MB
    float2*   buf1    = (float2*)(ws + (4ull << 20));      // 2 MB
    float*    probs   = (float*)(ws + (8ull << 20));       // 1 MB
    float*    partial = (float*)(ws + (16ull << 20));      // 4 MB

    kInit<<<256, 256, 0, stream>>>(buf0, qw);                       // L0 + L1 low
    kBC  <<<256, 256, 0, stream>>>(buf0, buf1, nullptr, qw, 1);     // L1 high + P
    kA   <<<256, 256, 0, stream>>>(buf1, qw, 2);
    kBC  <<<256, 256, 0, stream>>>(buf1, buf0, nullptr, qw, 2);
    kA   <<<256, 256, 0, stream>>>(buf0, qw, 3);
    kBC  <<<256, 256, 0, stream>>>(buf0, nullptr, probs, qw, 3);

    k_mm<<<NMM, 256, 0, stream>>>(probs, W, partial);
    k_finalize<<<64, 256, 0, stream>>>(partial, bias, x, out);
}

// Round 10
// 57.386 us; speedup vs baseline: 5.6933x; 1.1416x over previous
//
#include <hip/hip_runtime.h>
#include <math.h>

// QNN: all gates are GF(2)-convolutions and the CNOT cascade is a linear bit
// permutation P  =>  the 16 initial basis states evolve into XOR-translates
// of ONE simulated state: probs_j(i) = probs_0(i ^ P^4(j)).
// Simulate a single 2^18 complex state (2 MB), then
// logits[j][o] = sum_d probs_0(d ^ T_j) * W[o][d] + b[o];  (MFMA, bf16)
// out[b][o] = sigmoid(logits[idx_b][o]).
//
// Bit convention: wire w <-> bit p = 17-w.  P: out bit q (q<=16) =
// parity(i>>q); out bit 17 = parity(i & 0x1FFFF).
//
// Circuit passes are register-blocked: a thread owns 4 elements covering two
// gate bits -> 2 gates per round in registers; 5 rounds (kA/kInit, bits 0..9,
// 4 syncs) / 4 rounds (kBC, bits 10..17, 3 syncs). First round loads global
// into regs, last round stores regs to global (kBC: with P-scatter).

#define DIM (1 << 18)
#define NW 18
#define CH 128                      // k_mm d-columns per LDS stage
#define CPB 2                       // chunks per k_mm block
#define NMM (DIM / (CH * CPB))      // 1024 blocks

#define PAD16(i) ((i) + ((i) >> 4))

typedef short short8 __attribute__((ext_vector_type(8)));   // 8 bf16 (4 VGPRs)
typedef float f32x4  __attribute__((ext_vector_type(4)));   // MFMA accumulator

__device__ __forceinline__ unsigned perm18(unsigned i) {
    unsigned s = i;
    s ^= s >> 1; s ^= s >> 2; s ^= s >> 4; s ^= s >> 8; s ^= s >> 16;
    unsigned out = s & 0x1FFFFu;
    out |= ((s ^ (i >> 17)) & 1u) << 17;
    return out;
}

__device__ __forceinline__ unsigned pinv18(unsigned b) {
    unsigned t = b & 0x1FFFFu;                 // s_0..s_16
    unsigned u = (t ^ (t >> 1)) & 0xFFFFu;     // i_0..i_15
    unsigned i17 = ((b >> 17) ^ t) & 1u;
    unsigned i16 = ((t >> 16) ^ i17) & 1u;
    return u | (i16 << 16) | (i17 << 17);
}

__device__ __forceinline__ void bfly(float2& a0, float2& a1, float c, float s) {
    float2 n0 = make_float2(c * a0.x + s * a1.y, c * a0.y - s * a1.x);
    float2 n1 = make_float2(c * a1.x + s * a0.y, c * a1.y - s * a0.x);
    a0 = n0; a1 = n1;
}

__device__ __forceinline__ short f2bf(float x) {            // RNE fp32->bf16
    unsigned u = __float_as_uint(x);
    return (short)((u + 0x7FFFu + ((u >> 16) & 1u)) >> 16);
}

// 2-gate register round on bits (2R, 2R+1) of a 1024-element LDS tile.
template<int R>
__device__ __forceinline__ void ldsRound(float2* t, int m, const float2* gsh) {
    constexpr int B = 1 << (2 * R);
    int low = m & (B - 1);
    int high = m >> (2 * R);
    int ib = (high << (2 * R + 2)) | low;
    int p00 = PAD16(ib), p01 = PAD16(ib | B), p10 = PAD16(ib | (2 * B)), p11 = PAD16(ib | (3 * B));
    float2 e00 = t[p00], e01 = t[p01], e10 = t[p10], e11 = t[p11];
    float2 g0 = gsh[2 * R], g1 = gsh[2 * R + 1];
    bfly(e00, e01, g0.x, g0.y);
    bfly(e10, e11, g0.x, g0.y);
    bfly(e00, e10, g1.x, g1.y);
    bfly(e01, e11, g1.x, g1.y);
    t[p00] = e00; t[p01] = e01; t[p10] = e10; t[p11] = e11;
}

// ---- kInit: analytic layer-0 (post-P basis) + layer-1 gates bits 0..9 ------
__global__ __launch_bounds__(256) void kInit(float2* buf, const float* qw) {
    __shared__ float2 t[1088];
    __shared__ float2 gsh[10];
    int tid = threadIdx.x;
    if (tid < 10) {
        float th = qw[1 * NW + (17 - tid)] * 0.5f;
        gsh[tid] = make_float2(cosf(th), sinf(th));
    }
    float c[NW], s[NW];
#pragma unroll
    for (int w = 0; w < NW; ++w) {
        float th = qw[w] * 0.5f;
        c[w] = cosf(th); s[w] = sinf(th);
    }
    unsigned base = blockIdx.x * 1024u;
    float2 e[4];
#pragma unroll
    for (int b = 0; b < 4; ++b) {
        unsigned i = pinv18(base + 4 * tid + b);
        float m = 1.0f;
#pragma unroll
        for (int p = 0; p < 18; ++p)
            m *= ((i >> p) & 1u) ? s[17 - p] : c[17 - p];
        int k4 = __popc(i) & 3;
        if      (k4 == 0) e[b] = make_float2( m, 0.f);
        else if (k4 == 1) e[b] = make_float2(0.f, -m);
        else if (k4 == 2) e[b] = make_float2(-m, 0.f);
        else              e[b] = make_float2(0.f,  m);
    }
    __syncthreads();                       // gsh ready
    // round 0: bits 0,1 in registers
    bfly(e[0], e[1], gsh[0].x, gsh[0].y);
    bfly(e[2], e[3], gsh[0].x, gsh[0].y);
    bfly(e[0], e[2], gsh[1].x, gsh[1].y);
    bfly(e[1], e[3], gsh[1].x, gsh[1].y);
    int ib = 4 * tid;
    t[PAD16(ib)] = e[0]; t[PAD16(ib + 1)] = e[1]; t[PAD16(ib + 2)] = e[2]; t[PAD16(ib + 3)] = e[3];
    __syncthreads();
    ldsRound<1>(t, tid, gsh); __syncthreads();
    ldsRound<2>(t, tid, gsh); __syncthreads();
    ldsRound<3>(t, tid, gsh); __syncthreads();
    // round 4: bits 8,9 in registers, write global coalesced
    float2 f00 = t[PAD16(tid)], f01 = t[PAD16(tid + 256)];
    float2 f10 = t[PAD16(tid + 512)], f11 = t[PAD16(tid + 768)];
    bfly(f00, f01, gsh[8].x, gsh[8].y);
    bfly(f10, f11, gsh[8].x, gsh[8].y);
    bfly(f00, f10, gsh[9].x, gsh[9].y);
    bfly(f01, f11, gsh[9].x, gsh[9].y);
    buf[base + tid] = f00; buf[base + tid + 256] = f01;
    buf[base + tid + 512] = f10; buf[base + tid + 768] = f11;
}

// ---- kA: 10 RX gates on bits 0..9, in-place, contiguous 1024 tiles ---------
__global__ __launch_bounds__(256) void kA(float2* buf, const float* qw, int layer) {
    __shared__ float2 t[1088];
    __shared__ float2 gsh[10];
    int tid = threadIdx.x;
    if (tid < 10) {
        float th = qw[layer * NW + (17 - tid)] * 0.5f;
        gsh[tid] = make_float2(cosf(th), sinf(th));
    }
    unsigned base = blockIdx.x * 1024u;
    float2 e0 = buf[base + 4 * tid + 0];
    float2 e1 = buf[base + 4 * tid + 1];
    float2 e2 = buf[base + 4 * tid + 2];
    float2 e3 = buf[base + 4 * tid + 3];
    __syncthreads();                       // gsh ready
    bfly(e0, e1, gsh[0].x, gsh[0].y);
    bfly(e2, e3, gsh[0].x, gsh[0].y);
    bfly(e0, e2, gsh[1].x, gsh[1].y);
    bfly(e1, e3, gsh[1].x, gsh[1].y);
    int ib = 4 * tid;
    t[PAD16(ib)] = e0; t[PAD16(ib + 1)] = e1; t[PAD16(ib + 2)] = e2; t[PAD16(ib + 3)] = e3;
    __syncthreads();
    ldsRound<1>(t, tid, gsh); __syncthreads();
    ldsRound<2>(t, tid, gsh); __syncthreads();
    ldsRound<3>(t, tid, gsh); __syncthreads();
    float2 f00 = t[PAD16(tid)], f01 = t[PAD16(tid + 256)];
    float2 f10 = t[PAD16(tid + 512)], f11 = t[PAD16(tid + 768)];
    bfly(f00, f01, gsh[8].x, gsh[8].y);
    bfly(f10, f11, gsh[8].x, gsh[8].y);
    bfly(f00, f10, gsh[9].x, gsh[9].y);
    bfly(f01, f11, gsh[9].x, gsh[9].y);
    buf[base + tid] = f00; buf[base + tid + 256] = f01;
    buf[base + tid + 512] = f10; buf[base + tid + 768] = f11;
}

// ---- kBC: 8 RX gates on bits 10..17 + perm P scatter -----------------------
// tile: h in [0,256) = bits 10..17, lo in [0,4) = bits 0..1; block = bits 2..9.
// LDS element k = 4h + lo. Rounds on h-bit pairs; thread = (mh:6 | lo:2).
// If probs != nullptr, emit |amp|^2 (final layer).
__global__ __launch_bounds__(256) void kBC(const float2* __restrict__ in, float2* out,
                                           float* probs, const float* qw, int layer) {
    __shared__ float2 t[1088];
    __shared__ float2 gsh[8];
    int tid = threadIdx.x;
    if (tid < 8) {                              // h bit q -> wire 7-q
        float th = qw[layer * NW + (7 - tid)] * 0.5f;
        gsh[tid] = make_float2(cosf(th), sinf(th));
    }
    unsigned mblk = blockIdx.x;                 // bits 2..9
    int mh = tid >> 2, lo = tid & 3;
    unsigned ibase = (mblk << 2) | lo;
    // round 0: h bits 0,1 (global bits 10,11) from global
    float2 e0 = in[((unsigned)(4 * mh + 0) << 10) | ibase];
    float2 e1 = in[((unsigned)(4 * mh + 1) << 10) | ibase];
    float2 e2 = in[((unsigned)(4 * mh + 2) << 10) | ibase];
    float2 e3 = in[((unsigned)(4 * mh + 3) << 10) | ibase];
    __syncthreads();                       // gsh ready
    bfly(e0, e1, gsh[0].x, gsh[0].y);
    bfly(e2, e3, gsh[0].x, gsh[0].y);
    bfly(e0, e2, gsh[1].x, gsh[1].y);
    bfly(e1, e3, gsh[1].x, gsh[1].y);
    {
        int k = 4 * (4 * mh) + lo;             // h = 4*mh + b -> k = 16mh + 4b + lo
        t[PAD16(k)] = e0; t[PAD16(k + 4)] = e1; t[PAD16(k + 8)] = e2; t[PAD16(k + 12)] = e3;
    }
    __syncthreads();
    // round 1: h bits 2,3
    {
        int hb = ((mh >> 2) << 4) | (mh & 3);
        int k00 = 4 * hb + lo, k01 = 4 * (hb | 4) + lo, k10 = 4 * (hb | 8) + lo, k11 = 4 * (hb | 12) + lo;
        int p00 = PAD16(k00), p01 = PAD16(k01), p10 = PAD16(k10), p11 = PAD16(k11);
        float2 a0 = t[p00], a1 = t[p01], a2 = t[p10], a3 = t[p11];
        bfly(a0, a1, gsh[2].x, gsh[2].y);
        bfly(a2, a3, gsh[2].x, gsh[2].y);
        bfly(a0, a2, gsh[3].x, gsh[3].y);
        bfly(a1, a3, gsh[3].x, gsh[3].y);
        t[p00] = a0; t[p01] = a1; t[p10] = a2; t[p11] = a3;
    }
    __syncthreads();
    // round 2: h bits 4,5
    {
        int hb = ((mh >> 4) << 6) | (mh & 15);
        int k00 = 4 * hb + lo, k01 = 4 * (hb | 16) + lo, k10 = 4 * (hb | 32) + lo, k11 = 4 * (hb | 48) + lo;
        int p00 = PAD16(k00), p01 = PAD16(k01), p10 = PAD16(k10), p11 = PAD16(k11);
        float2 a0 = t[p00], a1 = t[p01], a2 = t[p10], a3 = t[p11];
        bfly(a0, a1, gsh[4].x, gsh[4].y);
        bfly(a2, a3, gsh[4].x, gsh[4].y);
        bfly(a0, a2, gsh[5].x, gsh[5].y);
        bfly(a1, a3, gsh[5].x, gsh[5].y);
        t[p00] = a0; t[p01] = a1; t[p10] = a2; t[p11] = a3;
    }
    __syncthreads();
    // round 3: h bits 6,7; gates in regs, then P-scatter to global
    {
        int k = 4 * mh + lo;                   // h = mh + {0,64,128,192}
        float2 a0 = t[PAD16(k)], a1 = t[PAD16(k + 256)], a2 = t[PAD16(k + 512)], a3 = t[PAD16(k + 768)];
        bfly(a0, a1, gsh[6].x, gsh[6].y);
        bfly(a2, a3, gsh[6].x, gsh[6].y);
        bfly(a0, a2, gsh[7].x, gsh[7].y);
        bfly(a1, a3, gsh[7].x, gsh[7].y);
        unsigned i0 = ((unsigned)(mh +   0) << 10) | ibase;
        unsigned i1 = ((unsigned)(mh +  64) << 10) | ibase;
        unsigned i2 = ((unsigned)(mh + 128) << 10) | ibase;
        unsigned i3 = ((unsigned)(mh + 192) << 10) | ibase;
        if (probs) {
            probs[perm18(i0)] = a0.x * a0.x + a0.y * a0.y;
            probs[perm18(i1)] = a1.x * a1.x + a1.y * a1.y;
            probs[perm18(i2)] = a2.x * a2.x + a2.y * a2.y;
            probs[perm18(i3)] = a3.x * a3.x + a3.y * a3.y;
        } else {
            out[perm18(i0)] = a0;
            out[perm18(i1)] = a1;
            out[perm18(i2)] = a2;
            out[perm18(i3)] = a3;
        }
    }
}

// ---- logits partials via MFMA: 1024 blocks x 2 chunks, reg prefetch --------
// 4 waves; wave w owns o-tile [16w,16w+16). Per chunk: 4x mfma_f32_16x16x32_bf16.
__global__ __launch_bounds__(256) void k_mm(const float* __restrict__ p0,
                                            const float* __restrict__ W,
                                            float* __restrict__ partial) {
    __shared__ short Wl[64][136];       // bf16, pitch 272 B
    __shared__ short Pl[16][136];
    __shared__ unsigned Tsh[16];
    int tid = threadIdx.x;
    if (tid < 16) {
        unsigned v = (unsigned)tid;
#pragma unroll
        for (int r = 0; r < 4; ++r) v = perm18(v);
        Tsh[tid] = v;
    }
    __syncthreads();

    unsigned d00 = (unsigned)blockIdx.x * (CH * CPB);
    int wrow = tid >> 5;                   // 0..7
    int wcol = (tid & 31) * 4;
    int prow = tid >> 7;                   // 0..1
    int pcol = tid & 127;
    unsigned Tp[8];
#pragma unroll
    for (int t = 0; t < 8; ++t) Tp[t] = Tsh[prow + 2 * t];

    int lane = tid & 63, wv = tid >> 6;    // wave -> o-tile 16*wv
    f32x4 acc = {0.f, 0.f, 0.f, 0.f};

    float4 wr[8];
    float  pr[8];

    // stage chunk 0 (fp32 -> bf16 in-register)
#pragma unroll
    for (int t = 0; t < 8; ++t)
        wr[t] = *(const float4*)&W[(size_t)(wrow + 8 * t) * DIM + d00 + wcol];
#pragma unroll
    for (int t = 0; t < 8; ++t)
        pr[t] = p0[(d00 ^ (Tp[t] & ~127u)) + pcol];
#pragma unroll
    for (int t = 0; t < 8; ++t) {
        short4 b = make_short4(f2bf(wr[t].x), f2bf(wr[t].y), f2bf(wr[t].z), f2bf(wr[t].w));
        *(short4*)&Wl[wrow + 8 * t][wcol] = b;
    }
#pragma unroll
    for (int t = 0; t < 8; ++t)
        Pl[prow + 2 * t][pcol ^ (Tp[t] & 127u)] = f2bf(pr[t]);
    __syncthreads();

    // issue chunk 1 loads (hide under chunk-0 MFMAs)
    {
        unsigned d1 = d00 + CH;
#pragma unroll
        for (int t = 0; t < 8; ++t)
            wr[t] = *(const float4*)&W[(size_t)(wrow + 8 * t) * DIM + d1 + wcol];
#pragma unroll
        for (int t = 0; t < 8; ++t)
            pr[t] = p0[(d1 ^ (Tp[t] & ~127u)) + pcol];
    }

    int arow = lane & 15, kg = (lane >> 4) * 8;
#pragma unroll
    for (int kk = 0; kk < 4; ++kk) {
        short8 a = *(const short8*)&Pl[arow][kk * 32 + kg];
        short8 b = *(const short8*)&Wl[16 * wv + arow][kk * 32 + kg];
        acc = __builtin_amdgcn_mfma_f32_16x16x32_bf16(a, b, acc, 0, 0, 0);
    }
    __syncthreads();

#pragma unroll
    for (int t = 0; t < 8; ++t) {
        short4 b = make_short4(f2bf(wr[t].x), f2bf(wr[t].y), f2bf(wr[t].z), f2bf(wr[t].w));
        *(short4*)&Wl[wrow + 8 * t][wcol] = b;
    }
#pragma unroll
    for (int t = 0; t < 8; ++t)
        Pl[prow + 2 * t][pcol ^ (Tp[t] & 127u)] = f2bf(pr[t]);
    __syncthreads();

#pragma unroll
    for (int kk = 0; kk < 4; ++kk) {
        short8 a = *(const short8*)&Pl[arow][kk * 32 + kg];
        short8 b = *(const short8*)&Wl[16 * wv + arow][kk * 32 + kg];
        acc = __builtin_amdgcn_mfma_f32_16x16x32_bf16(a, b, acc, 0, 0, 0);
    }

    float* dst = partial + (size_t)blockIdx.x * 1024;
#pragma unroll
    for (int r = 0; r < 4; ++r) {
        int jrow = (lane >> 4) * 4 + r;
        dst[jrow * 64 + 16 * wv + (lane & 15)] = acc[r];
    }
}

// ---- finalize: reduce partials -> logits; per-batch lookup + sigmoid -------
// 64 blocks; block b owns idx = b>>2, o in [(b&3)*16, +16).
__global__ __launch_bounds__(256) void k_finalize(const float* __restrict__ partial,
                                                  const float* __restrict__ bias,
                                                  const int* __restrict__ x,
                                                  float* __restrict__ out) {
    int b = blockIdx.x;
    int tid = threadIdx.x;
    int ji = tid & 15, ci = tid >> 4;
    int jo = b * 16 + ji;
    float sum = 0.f;
#pragma unroll 8
    for (int c = ci; c < NMM; c += 16)
        sum += partial[(size_t)c * 1024 + jo];
    __shared__ float red[16][17];
    __shared__ float lg[16];
    __shared__ int sidx[32];
    red[ci][ji] = sum;
    if (tid < 32) {
        const int* xb = x + (size_t)tid * (16384 * 4);
        sidx[tid] = 8 * xb[0] + 4 * xb[1] + 2 * xb[2] + xb[3];
    }
    __syncthreads();
    if (ci == 0) {
        float s = 0.f;
#pragma unroll
        for (int k = 0; k < 16; ++k) s += red[k][ji];
        lg[ji] = s + bias[jo & 63];
    }
    __syncthreads();
    int myidx = b >> 2, o0 = (b & 3) * 16;
#pragma unroll
    for (int r = 0; r < 2; ++r) {
        int slot = tid + 256 * r;          // 512 slots = 32 batches x 16 o's
        int bb = slot >> 4, k = slot & 15;
        if (sidx[bb] == myidx) {
            float z = lg[k];
            out[bb * 64 + o0 + k] = 1.f / (1.f + expf(-z));
        }
    }
}

extern "C" void kernel_launch(void* const* d_in, const int* in_sizes, int n_in,
                              void* d_out, int out_size, void* d_ws, size_t ws_size,
                              hipStream_t stream) {
    const int*   x    = (const int*)d_in[0];
    const float* qw   = (const float*)d_in[1];
    const float* W    = (const float*)d_in[2];
    const float* bias = (const float*)d_in[3];
    float* out = (float*)d_out;

    char* ws = (char*)d_ws;
    float2*   buf0    = (float2*)(ws + (1ull << 20));      // 2 MB
    float2*   buf1    = (float2*)(ws + (4ull << 20));      // 2 MB
    float*    probs   = (float*)(ws + (8ull << 20));       // 1 MB
    float*    partial = (float*)(ws + (16ull << 20));      // 4 MB

    kInit<<<256, 256, 0, stream>>>(buf0, qw);                       // L0 + L1 low
    kBC  <<<256, 256, 0, stream>>>(buf0, buf1, nullptr, qw, 1);     // L1 high + P
    kA   <<<256, 256, 0, stream>>>(buf1, qw, 2);
    kBC  <<<256, 256, 0, stream>>>(buf1, buf0, nullptr, qw, 2);
    kA   <<<256, 256, 0, stream>>>(buf0, qw, 3);
    kBC  <<<256, 256, 0, stream>>>(buf0, nullptr, probs, qw, 3);

    k_mm<<<NMM, 256, 0, stream>>>(probs, W, partial);
    k_finalize<<<64, 256, 0, stream>>>(partial, bias, x, out);
}

// Round 14
// 56.295 us; speedup vs baseline: 5.8036x; 1.0194x over previous
//
#include <hip/hip_runtime.h>
#include <math.h>

// QNN: all gates are GF(2)-convolutions and the CNOT cascade is a linear bit
// permutation P  =>  the 16 initial basis states evolve into XOR-translates
// of ONE simulated state: probs_j(i) = probs_0(i ^ P^4(j)).
// Simulate a single 2^18 complex state (2 MB), then
// logits[j][o] = sum_d probs_0(d ^ T_j) * W[o][d] + b[o];  (MFMA, bf16)
// out[b][o] = sigmoid(logits[idx_b][o]).
//
// Bit convention: wire w <-> bit p = 17-w.  P: out bit q (q<=16) =
// parity(i>>q); out bit 17 = parity(i & 0x1FFFF).
//
// Gate split per layer: kA = bits {0..8, 17} (10 gates), kBC = bits {9..16}
// (8 gates). P is folded into kA's LOAD (P^-1 maps a post-P tile spanning
// {bits0..8}x{bit17} with bits 9..16 fixed onto TWO contiguous 512-elem
// pre-P blocks, base and base^0x30000, low-9 inverse-Gray permuted). So kBC
// writes natural order (coalesced, in-place); no intermediate scatter. Only
// the final probs pass scatters (4B), keeping k_mm's proven gather.

#define DIM (1 << 18)
#define NW 18
#define CH 128                      // k_mm d-columns per LDS stage
#define CPB 4                       // chunks per k_mm block
#define NMM (DIM / (CH * CPB))      // 512 blocks

#define PAD16(i) ((i) + ((i) >> 4))

typedef short short8 __attribute__((ext_vector_type(8)));   // 8 bf16 (4 VGPRs)
typedef float f32x4  __attribute__((ext_vector_type(4)));   // MFMA accumulator

__device__ __forceinline__ unsigned perm18(unsigned i) {
    unsigned s = i;
    s ^= s >> 1; s ^= s >> 2; s ^= s >> 4; s ^= s >> 8; s ^= s >> 16;
    unsigned out = s & 0x1FFFFu;
    out |= ((s ^ (i >> 17)) & 1u) << 17;
    return out;
}

__device__ __forceinline__ unsigned pinv18(unsigned b) {
    unsigned t = b & 0x1FFFFu;                 // s_0..s_16
    unsigned u = (t ^ (t >> 1)) & 0xFFFFu;     // i_0..i_15
    unsigned i17 = ((b >> 17) ^ t) & 1u;
    unsigned i16 = ((t >> 16) ^ i17) & 1u;
    return u | (i16 << 16) | (i17 << 17);
}

__device__ __forceinline__ unsigned ginv9(unsigned x) {     // inverse Gray, 9b
    x ^= x >> 1; x ^= x >> 2; x ^= x >> 4; x ^= x >> 8;
    return x & 511u;
}

__device__ __forceinline__ void bfly(float2& a0, float2& a1, float c, float s) {
    float2 n0 = make_float2(c * a0.x + s * a1.y, c * a0.y - s * a1.x);
    float2 n1 = make_float2(c * a1.x + s * a0.y, c * a1.y - s * a0.x);
    a0 = n0; a1 = n1;
}

__device__ __forceinline__ short f2bf(float x) {            // RNE fp32->bf16
    unsigned u = __float_as_uint(x);
    return (short)((u + 0x7FFFu + ((u >> 16) & 1u)) >> 16);
}

// 2-gate register round on slot bits (RB, RB+1) of a 1024-slot LDS tile.
template<int RB>
__device__ __forceinline__ void slotRound(float2* t, int m, float2 g0, float2 g1) {
    constexpr int B = 1 << RB;
    int low = m & (B - 1);
    int high = m >> RB;
    int ib = (high << (RB + 2)) | low;
    int p00 = PAD16(ib), p01 = PAD16(ib | B), p10 = PAD16(ib | 2 * B), p11 = PAD16(ib | 3 * B);
    float2 e00 = t[p00], e01 = t[p01], e10 = t[p10], e11 = t[p11];
    bfly(e00, e01, g0.x, g0.y);
    bfly(e10, e11, g0.x, g0.y);
    bfly(e00, e10, g1.x, g1.y);
    bfly(e01, e11, g1.x, g1.y);
    t[p00] = e00; t[p01] = e01; t[p10] = e10; t[p11] = e11;
}

// shared tail for kA/kInit: rounds on slot bits (1,2),(3,4),(5,6),(7,8)+write.
// slot = (p17<<9)|bl; gsh[p] = gate for state bit p (p<=8), gsh[9] = bit 17.
__device__ __forceinline__ void kaTail(float2* t, int tid, const float2* gsh,
                                       float2* __restrict__ out, unsigned B9) {
    slotRound<1>(t, tid, gsh[1], gsh[2]); __syncthreads();
    slotRound<3>(t, tid, gsh[3], gsh[4]); __syncthreads();
    slotRound<5>(t, tid, gsh[5], gsh[6]); __syncthreads();
    // final round: slot bits 7,8 in regs, then coalesced natural write
    int low = tid & 127, high = tid >> 7;      // high = p17
    int ib = (high << 9) | low;
    float2 a0 = t[PAD16(ib)], a1 = t[PAD16(ib | 128)];
    float2 a2 = t[PAD16(ib | 256)], a3 = t[PAD16(ib | 384)];
    bfly(a0, a1, gsh[7].x, gsh[7].y);
    bfly(a2, a3, gsh[7].x, gsh[7].y);
    bfly(a0, a2, gsh[8].x, gsh[8].y);
    bfly(a1, a3, gsh[8].x, gsh[8].y);
    unsigned ob = ((unsigned)high << 17) | (B9 << 9) | (unsigned)low;
    out[ob] = a0; out[ob + 128] = a1; out[ob + 256] = a2; out[ob + 384] = a3;
}

// ---- kInit: analytic layer-0 (post-P basis) + layer-1 gates {0..8,17} ------
__global__ __launch_bounds__(256) void kInit(float2* __restrict__ out, const float* qw) {
    __shared__ float2 t[1088];
    __shared__ float2 gsh[10];
    int tid = threadIdx.x;
    if (tid < 10) {                            // layer 1 gates
        int p = (tid == 9) ? 17 : tid;
        float th = qw[1 * NW + (17 - p)] * 0.5f;
        gsh[tid] = make_float2(cosf(th), sinf(th));
    }
    float c[NW], s[NW];
#pragma unroll
    for (int w = 0; w < NW; ++w) {
        float th = qw[w] * 0.5f;
        c[w] = cosf(th); s[w] = sinf(th);
    }
    unsigned B9 = blockIdx.x;
    float2 e[2][2];                            // [p17][b0]
#pragma unroll
    for (int p17 = 0; p17 < 2; ++p17)
#pragma unroll
        for (int b0 = 0; b0 < 2; ++b0) {
            unsigned b = ((unsigned)p17 << 17) | (B9 << 9) | ((unsigned)tid << 1) | (unsigned)b0;
            unsigned i = pinv18(b);
            float m = 1.0f;
#pragma unroll
            for (int p = 0; p < 18; ++p)
                m *= ((i >> p) & 1u) ? s[17 - p] : c[17 - p];
            int k4 = __popc(i) & 3;
            if      (k4 == 0) e[p17][b0] = make_float2( m, 0.f);
            else if (k4 == 1) e[p17][b0] = make_float2(0.f, -m);
            else if (k4 == 2) e[p17][b0] = make_float2(-m, 0.f);
            else              e[p17][b0] = make_float2(0.f,  m);
        }
    __syncthreads();                           // gsh ready
    // round 0: state bit 0 (b0 pairs) and bit 17 (p17 pairs), in regs
    bfly(e[0][0], e[0][1], gsh[0].x, gsh[0].y);
    bfly(e[1][0], e[1][1], gsh[0].x, gsh[0].y);
    bfly(e[0][0], e[1][0], gsh[9].x, gsh[9].y);
    bfly(e[0][1], e[1][1], gsh[9].x, gsh[9].y);
    int sb = tid << 1;
    t[PAD16(sb)] = e[0][0];       t[PAD16(sb | 1)] = e[0][1];
    t[PAD16(sb | 512)] = e[1][0]; t[PAD16(sb | 513)] = e[1][1];
    __syncthreads();
    kaTail(t, tid, gsh, out, B9);
}

// ---- kA: P-folded gather + 10 gates {0..8,17}, natural write ---------------
__global__ __launch_bounds__(256) void kA(const float2* __restrict__ in,
                                          float2* __restrict__ out,
                                          const float* qw, int layer) {
    __shared__ float2 t[1088];
    __shared__ float2 gsh[10];
    int tid = threadIdx.x;
    if (tid < 10) {
        int p = (tid == 9) ? 17 : tid;
        float th = qw[layer * NW + (17 - p)] * 0.5f;
        gsh[tid] = make_float2(cosf(th), sinf(th));
    }
    unsigned B9 = blockIdx.x;
    unsigned C = pinv18(B9 << 9);
    unsigned c9 = C & 511u;
    unsigned base0 = C & ~511u;                // e = bl0^p17 = 0
    unsigned base1 = base0 ^ 0x30000u;         // e = 1
    float2 v[2][2];
#pragma unroll
    for (int ee = 0; ee < 2; ++ee)
#pragma unroll
        for (int r = 0; r < 2; ++r)
            v[ee][r] = in[(ee ? base1 : base0) + (unsigned)tid + 256u * r];
    // permuted LDS fill: global k -> slot (p17<<9)|bl, bl = ginv9(k^c9),
    // p17 = parity9(k^c9) ^ e
#pragma unroll
    for (int ee = 0; ee < 2; ++ee)
#pragma unroll
        for (int r = 0; r < 2; ++r) {
            unsigned k = (unsigned)tid + 256u * r;
            unsigned x = (k ^ c9) & 511u;
            unsigned bl = ginv9(x);
            unsigned p17 = ((unsigned)__popc(x) ^ (unsigned)ee) & 1u;
            t[PAD16((p17 << 9) | bl)] = v[ee][r];
        }
    __syncthreads();
    // round 0: slot bit 0 (state bit 0) + slot bit 9 (state bit 17)
    {
        int s00 = tid << 1;
        int p00 = PAD16(s00), p01 = PAD16(s00 | 1), p10 = PAD16(s00 | 512), p11 = PAD16(s00 | 513);
        float2 e00 = t[p00], e01 = t[p01], e10 = t[p10], e11 = t[p11];
        bfly(e00, e01, gsh[0].x, gsh[0].y);
        bfly(e10, e11, gsh[0].x, gsh[0].y);
        bfly(e00, e10, gsh[9].x, gsh[9].y);
        bfly(e01, e11, gsh[9].x, gsh[9].y);
        t[p00] = e00; t[p01] = e01; t[p10] = e10; t[p11] = e11;
    }
    __syncthreads();
    kaTail(t, tid, gsh, out, B9);
}

// ---- kBC: 8 RX gates on bits 9..16, natural in-place (or probs scatter) ----
// tile: h in [0,256) = bits 9..16, lo = bits 0..1; block = bits 2..8 + bit 17.
__global__ __launch_bounds__(256) void kBC(float2* __restrict__ buf, float* probs,
                                           const float* qw, int layer) {
    __shared__ float2 t[1088];
    __shared__ float2 gsh[8];
    int tid = threadIdx.x;
    if (tid < 8) {                              // state bit 9+q -> wire 8-q
        float th = qw[layer * NW + (8 - tid)] * 0.5f;
        gsh[tid] = make_float2(cosf(th), sinf(th));
    }
    unsigned blk = blockIdx.x;
    unsigned ibase = ((blk >> 7) << 17) | ((blk & 127u) << 2) | 0u;
    int mh = tid >> 2, lo = tid & 3;
    ibase |= (unsigned)lo;
    // round 0: h bits 0,1 (state bits 9,10) from global
    float2 e0 = buf[((unsigned)(4 * mh + 0) << 9) | ibase];
    float2 e1 = buf[((unsigned)(4 * mh + 1) << 9) | ibase];
    float2 e2 = buf[((unsigned)(4 * mh + 2) << 9) | ibase];
    float2 e3 = buf[((unsigned)(4 * mh + 3) << 9) | ibase];
    __syncthreads();                           // gsh ready
    bfly(e0, e1, gsh[0].x, gsh[0].y);
    bfly(e2, e3, gsh[0].x, gsh[0].y);
    bfly(e0, e2, gsh[1].x, gsh[1].y);
    bfly(e1, e3, gsh[1].x, gsh[1].y);
    {
        int k = 4 * (4 * mh) + lo;
        t[PAD16(k)] = e0; t[PAD16(k + 4)] = e1; t[PAD16(k + 8)] = e2; t[PAD16(k + 12)] = e3;
    }
    __syncthreads();
    // round 1: h bits 2,3
    {
        int hb = ((mh >> 2) << 4) | (mh & 3);
        int p00 = PAD16(4 * hb + lo), p01 = PAD16(4 * (hb | 4) + lo);
        int p10 = PAD16(4 * (hb | 8) + lo), p11 = PAD16(4 * (hb | 12) + lo);
        float2 a0 = t[p00], a1 = t[p01], a2 = t[p10], a3 = t[p11];
        bfly(a0, a1, gsh[2].x, gsh[2].y);
        bfly(a2, a3, gsh[2].x, gsh[2].y);
        bfly(a0, a2, gsh[3].x, gsh[3].y);
        bfly(a1, a3, gsh[3].x, gsh[3].y);
        t[p00] = a0; t[p01] = a1; t[p10] = a2; t[p11] = a3;
    }
    __syncthreads();
    // round 2: h bits 4,5
    {
        int hb = ((mh >> 4) << 6) | (mh & 15);
        int p00 = PAD16(4 * hb + lo), p01 = PAD16(4 * (hb | 16) + lo);
        int p10 = PAD16(4 * (hb | 32) + lo), p11 = PAD16(4 * (hb | 48) + lo);
        float2 a0 = t[p00], a1 = t[p01], a2 = t[p10], a3 = t[p11];
        bfly(a0, a1, gsh[4].x, gsh[4].y);
        bfly(a2, a3, gsh[4].x, gsh[4].y);
        bfly(a0, a2, gsh[5].x, gsh[5].y);
        bfly(a1, a3, gsh[5].x, gsh[5].y);
        t[p00] = a0; t[p01] = a1; t[p10] = a2; t[p11] = a3;
    }
    __syncthreads();
    // round 3: h bits 6,7; natural write-back (or probs P-scatter, final)
    {
        int k = 4 * mh + lo;
        float2 a0 = t[PAD16(k)], a1 = t[PAD16(k + 256)], a2 = t[PAD16(k + 512)], a3 = t[PAD16(k + 768)];
        bfly(a0, a1, gsh[6].x, gsh[6].y);
        bfly(a2, a3, gsh[6].x, gsh[6].y);
        bfly(a0, a2, gsh[7].x, gsh[7].y);
        bfly(a1, a3, gsh[7].x, gsh[7].y);
        unsigned i0 = ((unsigned)(mh +   0) << 9) | ibase;
        unsigned i1 = ((unsigned)(mh +  64) << 9) | ibase;
        unsigned i2 = ((unsigned)(mh + 128) << 9) | ibase;
        unsigned i3 = ((unsigned)(mh + 192) << 9) | ibase;
        if (probs) {
            probs[perm18(i0)] = a0.x * a0.x + a0.y * a0.y;
            probs[perm18(i1)] = a1.x * a1.x + a1.y * a1.y;
            probs[perm18(i2)] = a2.x * a2.x + a2.y * a2.y;
            probs[perm18(i3)] = a3.x * a3.x + a3.y * a3.y;
        } else {
            buf[i0] = a0; buf[i1] = a1; buf[i2] = a2; buf[i3] = a3;
        }
    }
}

// ---- logits partials via MFMA: 512 blocks x 4 chunks, named-reg prefetch ---
// 4 waves; wave w owns o-tile [16w,16w+16). Per chunk: 4x mfma_f32_16x16x32_bf16.
__global__ __launch_bounds__(256) void k_mm(const float* __restrict__ p0,
                                            const float* __restrict__ W,
                                            float* __restrict__ partial) {
    __shared__ short Wl[64][136];       // bf16, pitch 272 B
    __shared__ short Pl[16][136];
    __shared__ unsigned Tsh[16];
    int tid = threadIdx.x;
    if (tid < 16) {
        unsigned v = (unsigned)tid;
#pragma unroll
        for (int r = 0; r < 4; ++r) v = perm18(v);
        Tsh[tid] = v;
    }
    __syncthreads();

    unsigned d00 = (unsigned)blockIdx.x * (CH * CPB);
    int wrow = tid >> 5;                   // 0..7
    int wcol = (tid & 31) * 4;
    int prow = tid >> 7;                   // 0..1
    int pcol = tid & 127;
    unsigned Tp[8];
#pragma unroll
    for (int t = 0; t < 8; ++t) Tp[t] = Tsh[prow + 2 * t];

    int lane = tid & 63, wv = tid >> 6;    // wave -> o-tile 16*wv
    int arow = lane & 15, kg = (lane >> 4) * 8;
    f32x4 acc = {0.f, 0.f, 0.f, 0.f};

    float4 wr[8];
    float  pr[8];

    // prologue: stage chunk 0 (fp32 -> bf16 in-register)
#pragma unroll
    for (int t = 0; t < 8; ++t)
        wr[t] = *(const float4*)&W[(size_t)(wrow + 8 * t) * DIM + d00 + wcol];
#pragma unroll
    for (int t = 0; t < 8; ++t)
        pr[t] = p0[(d00 ^ (Tp[t] & ~127u)) + pcol];
#pragma unroll
    for (int t = 0; t < 8; ++t) {
        short4 b = make_short4(f2bf(wr[t].x), f2bf(wr[t].y), f2bf(wr[t].z), f2bf(wr[t].w));
        *(short4*)&Wl[wrow + 8 * t][wcol] = b;
    }
#pragma unroll
    for (int t = 0; t < 8; ++t)
        Pl[prow + 2 * t][pcol ^ (Tp[t] & 127u)] = f2bf(pr[t]);
    __syncthreads();

    for (int cc = 0; cc < CPB; ++cc) {
        if (cc + 1 < CPB) {                // issue next chunk loads (hidden)
            unsigned d1 = d00 + (unsigned)(cc + 1) * CH;
#pragma unroll
            for (int t = 0; t < 8; ++t)
                wr[t] = *(const float4*)&W[(size_t)(wrow + 8 * t) * DIM + d1 + wcol];
#pragma unroll
            for (int t = 0; t < 8; ++t)
                pr[t] = p0[(d1 ^ (Tp[t] & ~127u)) + pcol];
        }
#pragma unroll
        for (int kk = 0; kk < 4; ++kk) {
            short8 a = *(const short8*)&Pl[arow][kk * 32 + kg];
            short8 b = *(const short8*)&Wl[16 * wv + arow][kk * 32 + kg];
            acc = __builtin_amdgcn_mfma_f32_16x16x32_bf16(a, b, acc, 0, 0, 0);
        }
        __syncthreads();
        if (cc + 1 < CPB) {                // commit staged regs -> LDS
#pragma unroll
            for (int t = 0; t < 8; ++t) {
                short4 b = make_short4(f2bf(wr[t].x), f2bf(wr[t].y), f2bf(wr[t].z), f2bf(wr[t].w));
                *(short4*)&Wl[wrow + 8 * t][wcol] = b;
            }
#pragma unroll
            for (int t = 0; t < 8; ++t)
                Pl[prow + 2 * t][pcol ^ (Tp[t] & 127u)] = f2bf(pr[t]);
            __syncthreads();
        }
    }

    float* dst = partial + (size_t)blockIdx.x * 1024;
#pragma unroll
    for (int r = 0; r < 4; ++r) {
        int jrow = (lane >> 4) * 4 + r;
        dst[jrow * 64 + 16 * wv + (lane & 15)] = acc[r];
    }
}

// ---- finalize: reduce partials -> logits; per-batch lookup + sigmoid -------
// 64 blocks; block b owns idx = b>>2, o in [(b&3)*16, +16).
__global__ __launch_bounds__(256) void k_finalize(const float* __restrict__ partial,
                                                  const float* __restrict__ bias,
                                                  const int* __restrict__ x,
                                                  float* __restrict__ out) {
    int b = blockIdx.x;
    int tid = threadIdx.x;
    int ji = tid & 15, ci = tid >> 4;
    int jo = b * 16 + ji;
    float sum = 0.f;
#pragma unroll 8
    for (int c = ci; c < NMM; c += 16)
        sum += partial[(size_t)c * 1024 + jo];
    __shared__ float red[16][17];
    __shared__ float lg[16];
    __shared__ int sidx[32];
    red[ci][ji] = sum;
    if (tid < 32) {
        const int* xb = x + (size_t)tid * (16384 * 4);
        sidx[tid] = 8 * xb[0] + 4 * xb[1] + 2 * xb[2] + xb[3];
    }
    __syncthreads();
    if (ci == 0) {
        float s = 0.f;
#pragma unroll
        for (int k = 0; k < 16; ++k) s += red[k][ji];
        lg[ji] = s + bias[jo & 63];
    }
    __syncthreads();
    int myidx = b >> 2, o0 = (b & 3) * 16;
#pragma unroll
    for (int r = 0; r < 2; ++r) {
        int slot = tid + 256 * r;          // 512 slots = 32 batches x 16 o's
        int bb = slot >> 4, k = slot & 15;
        if (sidx[bb] == myidx) {
            float z = lg[k];
            out[bb * 64 + o0 + k] = 1.f / (1.f + expf(-z));
        }
    }
}

extern "C" void kernel_launch(void* const* d_in, const int* in_sizes, int n_in,
                              void* d_out, int out_size, void* d_ws, size_t ws_size,
                              hipStream_t stream) {
    const int*   x    = (const int*)d_in[0];
    const float* qw   = (const float*)d_in[1];
    const float* W    = (const float*)d_in[2];
    const float* bias = (const float*)d_in[3];
    float* out = (float*)d_out;

    char* ws = (char*)d_ws;
    float2*   buf0    = (float2*)(ws + (1ull << 20));      // 2 MB
    float2*   buf1    = (float2*)(ws + (4ull << 20));      // 2 MB
    float*    probs   = (float*)(ws + (8ull << 20));       // 1 MB
    float*    partial = (float*)(ws + (16ull << 20));      // 2 MB

    kInit<<<256, 256, 0, stream>>>(buf0, qw);               // L0 analytic + L1 {0..8,17}
    kBC  <<<256, 256, 0, stream>>>(buf0, nullptr, qw, 1);   // L1 {9..16}, in-place
    kA   <<<256, 256, 0, stream>>>(buf0, buf1, qw, 2);      // P-gather + L2 {0..8,17}
    kBC  <<<256, 256, 0, stream>>>(buf1, nullptr, qw, 2);   // L2 {9..16}, in-place
    kA   <<<256, 256, 0, stream>>>(buf1, buf0, qw, 3);      // P-gather + L3 {0..8,17}
    kBC  <<<256, 256, 0, stream>>>(buf0, probs, qw, 3);     // L3 {9..16} + P-scatter probs

    k_mm<<<NMM, 256, 0, stream>>>(probs, W, partial);
    k_finalize<<<64, 256, 0, stream>>>(partial, bias, x, out);
}